// Round 2
// baseline (1131.363 us; speedup 1.0000x reference)
//
#include <hip/hip_runtime.h>
#include <math.h>

// Problem constants: N=6000, D=256, H=8, DH=32, P=128, B=16. fp32 in/out (established R3).
#define N_GENES 6000
#define DM 256
#define NH 8
#define DHEAD 32
#define FF 1024
#define PMAX 128
#define MT 32     // rows per block in fused kernel
#define LDP 264   // padded LDS inner dim for u16 arrays (stride 132 words == 4 mod 32: 2-way max on b128 A-frag reads)
#define LDQ 268   // padded LDS inner dim for f32 arrays (stride 268 words == 12 mod 32: spreads LN-phase reads)

typedef unsigned short u16;
typedef unsigned int u32;
typedef __attribute__((ext_vector_type(8))) short s8bf;  // 8 bf16 in 4 VGPRs (guide-verified form)
typedef __attribute__((ext_vector_type(4))) float f4;

__device__ __forceinline__ f4 mfma_bf16(s8bf a, s8bf b, f4 c) {
    return __builtin_amdgcn_mfma_f32_16x16x32_bf16(a, b, c, 0, 0, 0);
}

__device__ __forceinline__ float bf2f(u16 u) { return __uint_as_float(((u32)u) << 16); }
__device__ __forceinline__ u16 f2bf(float f) {
    u32 x = __float_as_uint(f);
    return (u16)((x + 0x7fffu + ((x >> 16) & 1u)) >> 16);  // RNE
}
__device__ __forceinline__ float gelu_exact(float x) {
    return 0.5f * x * (1.0f + erff(x * 0.70710678118654752f));
}

// ---------------- fp32 -> bf16 weight conversion ----------------
__global__ __launch_bounds__(256) void cvt_kernel(const float* __restrict__ src,
                                                  u16* __restrict__ dst, int n) {
    int i = blockIdx.x * 256 + threadIdx.x;
    if (i < n) dst[i] = f2bf(src[i]);
}

// fp32 -> (hi, lo) bf16 pair: hi+lo reproduces fp32 to ~2^-17 relative (for fp32-accurate q-proj MFMA)
__global__ __launch_bounds__(256) void cvt_hilo_kernel(const float* __restrict__ src,
                                                       u16* __restrict__ hi, u16* __restrict__ lo, int n) {
    int i = blockIdx.x * 256 + threadIdx.x;
    if (i < n) {
        float x = src[i];
        u16 h = f2bf(x);
        hi[i] = h;
        lo[i] = f2bf(x - bf2f(h));
    }
}

// ---------------- k/v projection for the P gathered rows (fp32) ----------------
__global__ __launch_bounds__(256) void kvproj_kernel(
    const float* __restrict__ Hg, const int* __restrict__ pidx,
    const float* __restrict__ Win, const float* __restrict__ bin,
    float* __restrict__ kbuf, float* __restrict__ vbuf) {
    __shared__ float xs[DM];
    int p = blockIdx.x, d = threadIdx.x;
    int row = pidx[p];
    xs[d] = Hg[(size_t)row * DM + d];
    __syncthreads();
    const float4* wk = (const float4*)(Win + (size_t)(DM + d) * DM);
    const float4* wv = (const float4*)(Win + (size_t)(2 * DM + d) * DM);
    float ak = bin[DM + d];
    float av = bin[2 * DM + d];
    #pragma unroll 4
    for (int k = 0; k < DM / 4; ++k) {
        float4 a = wk[k], b = wv[k];
        float x0 = xs[4*k], x1 = xs[4*k+1], x2 = xs[4*k+2], x3 = xs[4*k+3];
        ak += a.x * x0 + a.y * x1 + a.z * x2 + a.w * x3;
        av += b.x * x0 + b.y * x1 + b.z * x2 + b.w * x3;
    }
    kbuf[(size_t)p * DM + d] = ak;
    vbuf[(size_t)p * DM + d] = av;
}

// ==== fully fused: q-proj(MFMA hi/lo) + scores + softmax + ctx + outproj + LN1 + FFN + LN2 ====
// One block per 32 output rows (b,n). No ctx intermediate in HBM.
// LDS regions: reg1 (34.3KB) time-shared: xq(f32 q) -> sb(f32 GEMM dumps) -> hb(u16 hidden) -> sb.
__global__ __launch_bounds__(256, 3) void fused_all_kernel(
    const float* __restrict__ Hg,
    const u16* __restrict__ WqhB, const u16* __restrict__ WqlB,
    const float* __restrict__ bin,
    const float* __restrict__ kbuf, const float* __restrict__ vbuf,
    const int* __restrict__ assign,
    const u16* __restrict__ WoB, const float* __restrict__ bout,
    const u16* __restrict__ W1B, const float* __restrict__ b1,
    const u16* __restrict__ W2B, const float* __restrict__ b2,
    const float* __restrict__ g1, const float* __restrict__ bb1,
    const float* __restrict__ g2, const float* __restrict__ bb2,
    float* __restrict__ out, int P, int B) {

    __shared__ __align__(16) char reg1_raw[MT * LDQ * 4];   // 34,304 B time-shared region
    __shared__ __align__(16) u16 xb[MT][LDP];               // 16,896 B: ctx(bf16) then x(bf16)
    __shared__ int asg[PMAX];
    __shared__ int startb[16];
    __shared__ int cntb[16];
    __shared__ float hasb[16];
    __shared__ int rown[MT];
    __shared__ int rowbv[MT];

    float (*xq)[LDQ] = (float(*)[LDQ])reg1_raw;  // q fp32 (phase 1-2)
    float (*sb)[LDQ] = (float(*)[LDQ])reg1_raw;  // GEMM dump fp32 (phase 3, 5)
    u16  (*hb)[LDP]  = (u16 (*)[LDP])reg1_raw;   // hidden bf16 (phase 4)

    const f4 fzero = {0.f, 0.f, 0.f, 0.f};
    int tid = threadIdx.x;
    int wv = tid >> 6, l = tid & 63;
    int l15 = l & 15, q8 = (l >> 4) * 8, q4 = (l >> 4) * 4;
    size_t row0 = (size_t)blockIdx.x * MT;

    // ---- P0: batch bookkeeping ----
    if (tid < P) asg[tid] = assign[tid];
    if (tid < MT) {
        size_t gr = row0 + tid;
        rown[tid] = (int)(gr % N_GENES);
        rowbv[tid] = (int)(gr / N_GENES);
    }
    __syncthreads();
    if (tid < B) {
        int s = 0, c = 0;
        for (int p = 0; p < P; ++p) { int a = asg[p]; s += (a < tid); c += (a == tid); }
        startb[tid] = s; cntb[tid] = c; hasb[tid] = c ? 1.f : 0.f;
    }
    __syncthreads();

    // ---- P1: q = (Hg @ Wq^T + bq) * scale, fp32-accurate via hi/lo bf16 (3 MFMAs) -> xq ----
    {
        f4 acc[2][4] = {fzero, fzero, fzero, fzero, fzero, fzero, fzero, fzero};
        int n0 = rown[l15], n1 = rown[16 + l15];
        const float* h0 = Hg + (size_t)n0 * DM;
        const float* h1 = Hg + (size_t)n1 * DM;
        for (int k0 = 0; k0 < DM; k0 += 32) {
            s8bf a0h, a0l, a1h, a1l;
            {
                float4 f0 = *(const float4*)(h0 + k0 + q8);
                float4 f1 = *(const float4*)(h0 + k0 + q8 + 4);
                float xv0[8] = {f0.x, f0.y, f0.z, f0.w, f1.x, f1.y, f1.z, f1.w};
                #pragma unroll
                for (int j = 0; j < 8; ++j) {
                    u16 hh = f2bf(xv0[j]);
                    a0h[j] = (short)hh;
                    a0l[j] = (short)f2bf(xv0[j] - bf2f(hh));
                }
                float4 e0 = *(const float4*)(h1 + k0 + q8);
                float4 e1 = *(const float4*)(h1 + k0 + q8 + 4);
                float xv1[8] = {e0.x, e0.y, e0.z, e0.w, e1.x, e1.y, e1.z, e1.w};
                #pragma unroll
                for (int j = 0; j < 8; ++j) {
                    u16 hh = f2bf(xv1[j]);
                    a1h[j] = (short)hh;
                    a1l[j] = (short)f2bf(xv1[j] - bf2f(hh));
                }
            }
            #pragma unroll
            for (int nt = 0; nt < 4; ++nt) {
                int nn = wv * 64 + nt * 16 + l15;
                s8bf bh = *(const s8bf*)&WqhB[(size_t)nn * DM + k0 + q8];
                s8bf bl = *(const s8bf*)&WqlB[(size_t)nn * DM + k0 + q8];
                acc[0][nt] = mfma_bf16(a0h, bh, acc[0][nt]);
                acc[0][nt] = mfma_bf16(a0h, bl, acc[0][nt]);
                acc[0][nt] = mfma_bf16(a0l, bh, acc[0][nt]);
                acc[1][nt] = mfma_bf16(a1h, bh, acc[1][nt]);
                acc[1][nt] = mfma_bf16(a1h, bl, acc[1][nt]);
                acc[1][nt] = mfma_bf16(a1l, bh, acc[1][nt]);
            }
        }
        #pragma unroll
        for (int nt = 0; nt < 4; ++nt) {
            int nn = wv * 64 + nt * 16 + l15;
            float bq = bin[nn];
            #pragma unroll
            for (int mt = 0; mt < 2; ++mt)
                #pragma unroll
                for (int r = 0; r < 4; ++r)
                    xq[mt * 16 + q4 + r][nn] = (acc[mt][nt][r] + bq) * 0.17677669529663687f;
        }
    }
    __syncthreads();

    // ---- P2: scores + softmax + ctx. Thread t owns (row r = t>>3, head h = t&7). ----
    // Slice length avg P/B = 8; dots are recomputed per pass (robust for any cnt, no LDS/regs blowup).
    {
        int r = tid >> 3, h = tid & 7;
        int b = rowbv[r];
        int s = startb[b], c = cntb[b];
        float4 qv[8];
        const float* qrow = xq[r] + h * DHEAD;
        #pragma unroll
        for (int e = 0; e < 8; ++e) qv[e] = *(const float4*)(qrow + 4 * e);
        float4 cx[8];
        #pragma unroll
        for (int e = 0; e < 8; ++e) cx[e] = make_float4(0.f, 0.f, 0.f, 0.f);
        if (c > 0) {
            const float* kb = kbuf + h * DHEAD;
            float m = -INFINITY;
            for (int i = 0; i < c; ++i) {
                const float4* kr = (const float4*)(kb + (size_t)(s + i) * DM);
                float d = 0.f;
                #pragma unroll
                for (int e = 0; e < 8; ++e) {
                    float4 kv = kr[e];
                    d += qv[e].x * kv.x + qv[e].y * kv.y + qv[e].z * kv.z + qv[e].w * kv.w;
                }
                m = fmaxf(m, d);
            }
            float sum = 0.f;
            for (int i = 0; i < c; ++i) {
                const float4* kr = (const float4*)(kb + (size_t)(s + i) * DM);
                float d = 0.f;
                #pragma unroll
                for (int e = 0; e < 8; ++e) {
                    float4 kv = kr[e];
                    d += qv[e].x * kv.x + qv[e].y * kv.y + qv[e].z * kv.z + qv[e].w * kv.w;
                }
                sum += __expf(d - m);
            }
            float inv = 1.0f / sum;
            const float* vb = vbuf + h * DHEAD;
            for (int i = 0; i < c; ++i) {
                const float4* kr = (const float4*)(kb + (size_t)(s + i) * DM);
                float d = 0.f;
                #pragma unroll
                for (int e = 0; e < 8; ++e) {
                    float4 kv = kr[e];
                    d += qv[e].x * kv.x + qv[e].y * kv.y + qv[e].z * kv.z + qv[e].w * kv.w;
                }
                float w = __expf(d - m) * inv;
                const float4* vr = (const float4*)(vb + (size_t)(s + i) * DM);
                #pragma unroll
                for (int e = 0; e < 8; ++e) {
                    float4 vvv = vr[e];
                    cx[e].x += w * vvv.x; cx[e].y += w * vvv.y;
                    cx[e].z += w * vvv.z; cx[e].w += w * vvv.w;
                }
            }
        }
        // ctx -> xb as bf16 (feeds GEMM0 A-frags directly; zeros for empty batch)
        u16* xrow = &xb[r][h * DHEAD];
        #pragma unroll
        for (int e = 0; e < 8; ++e) {
            *(u32*)(xrow + 4 * e)     = (u32)f2bf(cx[e].x) | ((u32)f2bf(cx[e].y) << 16);
            *(u32*)(xrow + 4 * e + 2) = (u32)f2bf(cx[e].z) | ((u32)f2bf(cx[e].w) << 16);
        }
    }
    __syncthreads();

    // ---- P3: GEMM0: attn_raw = ctx @ Wout^T -> sb (xq dead) ----
    {
        f4 acc[2][4] = {fzero, fzero, fzero, fzero, fzero, fzero, fzero, fzero};
        for (int k0 = 0; k0 < DM; k0 += 32) {
            s8bf a0 = *(const s8bf*)&xb[l15][k0 + q8];
            s8bf a1 = *(const s8bf*)&xb[16 + l15][k0 + q8];
            #pragma unroll
            for (int nt = 0; nt < 4; ++nt) {
                int nn = wv * 64 + nt * 16 + l15;
                s8bf wfrag = *(const s8bf*)&WoB[(size_t)nn * DM + k0 + q8];
                acc[0][nt] = mfma_bf16(a0, wfrag, acc[0][nt]);
                acc[1][nt] = mfma_bf16(a1, wfrag, acc[1][nt]);
            }
        }
        #pragma unroll
        for (int mt = 0; mt < 2; ++mt)
            #pragma unroll
            for (int nt = 0; nt < 4; ++nt)
                #pragma unroll
                for (int r = 0; r < 4; ++r)
                    sb[mt * 16 + q4 + r][wv * 64 + nt * 16 + l15] = acc[mt][nt][r];
    }
    __syncthreads();

    // ---- LN1: t = H + has*(sb + bout); x -> xb (bf16) ----
    {
        int r = tid >> 3, cg = (tid & 7) * 32;
        float has = hasb[rowbv[r]];
        const float* hp = Hg + (size_t)rown[r] * DM + cg;
        const float* bo = bout + cg;
        float tv[32];
        float sum = 0.f;
        #pragma unroll
        for (int j = 0; j < 32; j += 4) {
            float4 hv = *(const float4*)(hp + j);
            float4 bv = *(const float4*)(bo + j);
            float t0 = hv.x + has * (sb[r][cg + j]     + bv.x);
            float t1 = hv.y + has * (sb[r][cg + j + 1] + bv.y);
            float t2 = hv.z + has * (sb[r][cg + j + 2] + bv.z);
            float t3 = hv.w + has * (sb[r][cg + j + 3] + bv.w);
            tv[j] = t0; tv[j+1] = t1; tv[j+2] = t2; tv[j+3] = t3;
            sum += t0 + t1 + t2 + t3;
        }
        sum += __shfl_xor(sum, 1, 8); sum += __shfl_xor(sum, 2, 8); sum += __shfl_xor(sum, 4, 8);
        float mu = sum * (1.0f / DM);
        float vs = 0.f;
        #pragma unroll
        for (int j = 0; j < 32; ++j) { float dd = tv[j] - mu; vs += dd * dd; }
        vs += __shfl_xor(vs, 1, 8); vs += __shfl_xor(vs, 2, 8); vs += __shfl_xor(vs, 4, 8);
        float rs = rsqrtf(vs * (1.0f / DM) + 1e-5f);
        #pragma unroll
        for (int j = 0; j < 32; j += 2) {
            float x0 = (tv[j]     - mu) * rs * g1[cg + j]     + bb1[cg + j];
            float x1 = (tv[j + 1] - mu) * rs * g1[cg + j + 1] + bb1[cg + j + 1];
            *(u32*)&xb[r][cg + j] = (u32)f2bf(x0) | ((u32)f2bf(x1) << 16);
        }
    }
    __syncthreads();

    // ---- P4: FFN: GEMM1 (+b1, GELU) chunked 4x256 -> hb (aliases sb, now dead); GEMM2 accumulates ----
    f4 acc2[2][4] = {fzero, fzero, fzero, fzero, fzero, fzero, fzero, fzero};
    for (int ch = 0; ch < 4; ++ch) {
        f4 acc1[2][4] = {fzero, fzero, fzero, fzero, fzero, fzero, fzero, fzero};
        for (int k0 = 0; k0 < DM; k0 += 32) {
            s8bf a0 = *(const s8bf*)&xb[l15][k0 + q8];
            s8bf a1 = *(const s8bf*)&xb[16 + l15][k0 + q8];
            #pragma unroll
            for (int nt = 0; nt < 4; ++nt) {
                int nn = ch * 256 + wv * 64 + nt * 16 + l15;
                s8bf wfrag = *(const s8bf*)&W1B[(size_t)nn * DM + k0 + q8];
                acc1[0][nt] = mfma_bf16(a0, wfrag, acc1[0][nt]);
                acc1[1][nt] = mfma_bf16(a1, wfrag, acc1[1][nt]);
            }
        }
        #pragma unroll
        for (int nt = 0; nt < 4; ++nt) {
            int cl = wv * 64 + nt * 16 + l15;
            float bb = b1[ch * 256 + cl];
            #pragma unroll
            for (int mt = 0; mt < 2; ++mt)
                #pragma unroll
                for (int r = 0; r < 4; ++r)
                    hb[mt * 16 + q4 + r][cl] = f2bf(gelu_exact(acc1[mt][nt][r] + bb));
        }
        __syncthreads();
        for (int k0 = 0; k0 < DM; k0 += 32) {
            s8bf a0 = *(const s8bf*)&hb[l15][k0 + q8];
            s8bf a1 = *(const s8bf*)&hb[16 + l15][k0 + q8];
            #pragma unroll
            for (int nt = 0; nt < 4; ++nt) {
                int nn = wv * 64 + nt * 16 + l15;
                s8bf wfrag = *(const s8bf*)&W2B[(size_t)nn * FF + ch * 256 + k0 + q8];
                acc2[0][nt] = mfma_bf16(a0, wfrag, acc2[0][nt]);
                acc2[1][nt] = mfma_bf16(a1, wfrag, acc2[1][nt]);
            }
        }
        __syncthreads();
    }
    #pragma unroll
    for (int mt = 0; mt < 2; ++mt)
        #pragma unroll
        for (int nt = 0; nt < 4; ++nt)
            #pragma unroll
            for (int r = 0; r < 4; ++r)
                sb[mt * 16 + q4 + r][wv * 64 + nt * 16 + l15] = acc2[mt][nt][r];
    __syncthreads();

    // ---- LN2: t = x + (ffn + b2); write result to out (fp32) ----
    {
        int r = tid >> 3, cg = (tid & 7) * 32;
        size_t gr = row0 + r;
        const float* bp = b2 + cg;
        float tv[32];
        float sum = 0.f;
        #pragma unroll
        for (int j = 0; j < 32; j += 4) {
            float4 bv = *(const float4*)(bp + j);
            float t0 = bf2f(xb[r][cg + j])     + sb[r][cg + j]     + bv.x;
            float t1 = bf2f(xb[r][cg + j + 1]) + sb[r][cg + j + 1] + bv.y;
            float t2 = bf2f(xb[r][cg + j + 2]) + sb[r][cg + j + 2] + bv.z;
            float t3 = bf2f(xb[r][cg + j + 3]) + sb[r][cg + j + 3] + bv.w;
            tv[j] = t0; tv[j+1] = t1; tv[j+2] = t2; tv[j+3] = t3;
            sum += t0 + t1 + t2 + t3;
        }
        sum += __shfl_xor(sum, 1, 8); sum += __shfl_xor(sum, 2, 8); sum += __shfl_xor(sum, 4, 8);
        float mu = sum * (1.0f / DM);
        float vs = 0.f;
        #pragma unroll
        for (int j = 0; j < 32; ++j) { float dd = tv[j] - mu; vs += dd * dd; }
        vs += __shfl_xor(vs, 1, 8); vs += __shfl_xor(vs, 2, 8); vs += __shfl_xor(vs, 4, 8);
        float rs = rsqrtf(vs * (1.0f / DM) + 1e-5f);
        float* op = out + gr * DM + cg;
        #pragma unroll
        for (int j = 0; j < 32; j += 4) {
            float4 y;
            y.x = (tv[j]     - mu) * rs * g2[cg + j]     + bb2[cg + j];
            y.y = (tv[j + 1] - mu) * rs * g2[cg + j + 1] + bb2[cg + j + 1];
            y.z = (tv[j + 2] - mu) * rs * g2[cg + j + 2] + bb2[cg + j + 2];
            y.w = (tv[j + 3] - mu) * rs * g2[cg + j + 3] + bb2[cg + j + 3];
            *(float4*)(op + j) = y;
        }
    }
}

// ================= fallback path (ws too small for weight staging): R3-proven VALU =================
__global__ __launch_bounds__(256) void attn_fb_kernel(
    const float* __restrict__ Hg, const float* __restrict__ kbuf, const float* __restrict__ vbuf,
    const int* __restrict__ assign, const float* __restrict__ Win, const float* __restrict__ bin,
    const float* __restrict__ Wout, const float* __restrict__ bout,
    const float* __restrict__ ln1g, const float* __restrict__ ln1b,
    float* __restrict__ xout, int P) {
    __shared__ float qs[DM];
    __shared__ float hrow[DM];
    __shared__ float sc[NH][PMAX + 1];
    __shared__ float ctxs[DM];
    __shared__ int asg[PMAX];
    __shared__ float red[4];

    int n = blockIdx.x, b = blockIdx.y, tid = threadIdx.x;
    if (tid < P) asg[tid] = assign[tid];
    hrow[tid] = Hg[(size_t)n * DM + tid];
    __syncthreads();
    {
        const float4* wr = (const float4*)(Win + (size_t)tid * DM);
        float acc = bin[tid];
        #pragma unroll 4
        for (int k = 0; k < DM / 4; ++k) {
            float4 w = wr[k];
            acc += w.x * hrow[4*k] + w.y * hrow[4*k+1] + w.z * hrow[4*k+2] + w.w * hrow[4*k+3];
        }
        qs[tid] = acc * 0.17677669529663687f;
        __syncthreads();
    }
    int start = 0, cnt = 0;
    for (int p = 0; p < P; ++p) { int a = asg[p]; start += (a < b); cnt += (a == b); }
    for (int idx = tid; idx < NH * cnt; idx += 256) {
        int h = idx & (NH - 1), pl = idx >> 3;
        const float* krow = kbuf + (size_t)(start + pl) * DM + h * DHEAD;
        const float* qh = qs + h * DHEAD;
        float acc = 0.f;
        #pragma unroll
        for (int e = 0; e < DHEAD; ++e) acc += qh[e] * krow[e];
        sc[h][pl] = acc;
    }
    __syncthreads();
    if (cnt > 0) {
        int h = tid >> 5, ll = tid & 31;
        float m = -INFINITY;
        for (int p = ll; p < cnt; p += 32) m = fmaxf(m, sc[h][p]);
        #pragma unroll
        for (int off = 16; off > 0; off >>= 1) m = fmaxf(m, __shfl_xor(m, off, 32));
        float s = 0.f;
        for (int p = ll; p < cnt; p += 32) { float e = __expf(sc[h][p] - m); sc[h][p] = e; s += e; }
        #pragma unroll
        for (int off = 16; off > 0; off >>= 1) s += __shfl_xor(s, off, 32);
        float inv = 1.0f / s;
        for (int p = ll; p < cnt; p += 32) sc[h][p] *= inv;
    }
    __syncthreads();
    {
        int hh = tid >> 5, e = tid & 31;
        float acc = 0.f;
        for (int p = 0; p < cnt; ++p)
            acc += sc[hh][p] * vbuf[(size_t)(start + p) * DM + hh * DHEAD + e];
        ctxs[tid] = acc;
    }
    __syncthreads();
    float ao = 0.f;
    if (cnt > 0) {
        ao = bout[tid];
        const float4* wr = (const float4*)(Wout + (size_t)tid * DM);
        #pragma unroll 4
        for (int k = 0; k < DM / 4; ++k) {
            float4 w = wr[k];
            ao += w.x * ctxs[4*k] + w.y * ctxs[4*k+1] + w.z * ctxs[4*k+2] + w.w * ctxs[4*k+3];
        }
    }
    float t = hrow[tid] + ao;
    {
        float v = t;
        #pragma unroll
        for (int off = 32; off > 0; off >>= 1) v += __shfl_down(v, off, 64);
        if ((tid & 63) == 0) red[tid >> 6] = v;
        __syncthreads();
        float mu = (red[0] + red[1] + red[2] + red[3]) * (1.0f / DM);
        __syncthreads();
        float dv = t - mu, v2 = dv * dv;
        #pragma unroll
        for (int off = 32; off > 0; off >>= 1) v2 += __shfl_down(v2, off, 64);
        if ((tid & 63) == 0) red[tid >> 6] = v2;
        __syncthreads();
        float var = (red[0] + red[1] + red[2] + red[3]) * (1.0f / DM);
        float xv = dv * rsqrtf(var + 1e-5f) * ln1g[tid] + ln1b[tid];
        xout[((size_t)b * N_GENES + n) * DM + tid] = xv;
    }
}

__global__ __launch_bounds__(256) void ffn_fb_kernel(
    float* __restrict__ xio, const float* __restrict__ W1, const float* __restrict__ b1,
    const float* __restrict__ W2, const float* __restrict__ b2,
    const float* __restrict__ ln2g, const float* __restrict__ ln2b) {
    __shared__ float xs[4][DM];
    __shared__ float hs[4][FF];
    __shared__ float red[4];
    int tid = threadIdx.x;
    size_t row0 = (size_t)blockIdx.x * 4;
    for (int i = tid; i < 4 * DM; i += 256)
        ((float*)xs)[i] = xio[row0 * DM + i];
    __syncthreads();
    for (int oi = 0; oi < FF / 256; ++oi) {
        int o = oi * 256 + tid;
        float bb = b1[o];
        float a0 = bb, a1 = bb, a2 = bb, a3 = bb;
        const float4* wr = (const float4*)(W1 + (size_t)o * DM);
        #pragma unroll 2
        for (int k = 0; k < DM / 4; ++k) {
            float4 w = wr[k];
            a0 += w.x * xs[0][4*k] + w.y * xs[0][4*k+1] + w.z * xs[0][4*k+2] + w.w * xs[0][4*k+3];
            a1 += w.x * xs[1][4*k] + w.y * xs[1][4*k+1] + w.z * xs[1][4*k+2] + w.w * xs[1][4*k+3];
            a2 += w.x * xs[2][4*k] + w.y * xs[2][4*k+1] + w.z * xs[2][4*k+2] + w.w * xs[2][4*k+3];
            a3 += w.x * xs[3][4*k] + w.y * xs[3][4*k+1] + w.z * xs[3][4*k+2] + w.w * xs[3][4*k+3];
        }
        hs[0][o] = gelu_exact(a0); hs[1][o] = gelu_exact(a1);
        hs[2][o] = gelu_exact(a2); hs[3][o] = gelu_exact(a3);
    }
    __syncthreads();
    int d = tid;
    float bb2 = b2[d];
    float c0 = bb2, c1 = bb2, c2 = bb2, c3 = bb2;
    const float4* wr = (const float4*)(W2 + (size_t)d * FF);
    #pragma unroll 2
    for (int k = 0; k < FF / 4; ++k) {
        float4 w = wr[k];
        c0 += w.x * hs[0][4*k] + w.y * hs[0][4*k+1] + w.z * hs[0][4*k+2] + w.w * hs[0][4*k+3];
        c1 += w.x * hs[1][4*k] + w.y * hs[1][4*k+1] + w.z * hs[1][4*k+2] + w.w * hs[1][4*k+3];
        c2 += w.x * hs[2][4*k] + w.y * hs[2][4*k+1] + w.z * hs[2][4*k+2] + w.w * hs[2][4*k+3];
        c3 += w.x * hs[3][4*k] + w.y * hs[3][4*k+1] + w.z * hs[3][4*k+2] + w.w * hs[3][4*k+3];
    }
    float cr[4] = {c0, c1, c2, c3};
    float g = ln2g[d], bln = ln2b[d];
    #pragma unroll
    for (int r = 0; r < 4; ++r) {
        float t = cr[r] + xs[r][d];
        float v = t;
        #pragma unroll
        for (int off = 32; off > 0; off >>= 1) v += __shfl_down(v, off, 64);
        if ((tid & 63) == 0) red[tid >> 6] = v;
        __syncthreads();
        float mu = (red[0] + red[1] + red[2] + red[3]) * (1.0f / DM);
        __syncthreads();
        float dv = t - mu, v2 = dv * dv;
        #pragma unroll
        for (int off = 32; off > 0; off >>= 1) v2 += __shfl_down(v2, off, 64);
        if ((tid & 63) == 0) red[tid >> 6] = v2;
        __syncthreads();
        float var = (red[0] + red[1] + red[2] + red[3]) * (1.0f / DM);
        float y = dv * rsqrtf(var + 1e-5f) * g + bln;
        xio[(row0 + r) * DM + d] = y;
        __syncthreads();
    }
}

extern "C" void kernel_launch(void* const* d_in, const int* in_sizes, int n_in,
                              void* d_out, int out_size, void* d_ws, size_t ws_size,
                              hipStream_t stream) {
    const float* Hg   = (const float*)d_in[0];
    const int* pidx   = (const int*)d_in[1];
    const int* assign = (const int*)d_in[2];
    const float* in_w = (const float*)d_in[4];
    const float* in_b = (const float*)d_in[5];
    const float* out_w= (const float*)d_in[6];
    const float* out_b= (const float*)d_in[7];
    const float* w1   = (const float*)d_in[8];
    const float* b1   = (const float*)d_in[9];
    const float* w2   = (const float*)d_in[10];
    const float* b2   = (const float*)d_in[11];
    const float* g1   = (const float*)d_in[12];
    const float* bb1  = (const float*)d_in[13];
    const float* g2   = (const float*)d_in[14];
    const float* bb2  = (const float*)d_in[15];

    int P = in_sizes[1];
    int B = out_size / (N_GENES * DM);
    size_t nrows = (size_t)B * N_GENES;
    float* out = (float*)d_out;

    size_t woB = (size_t)DM * DM;          // 65536
    size_t w1B = (size_t)FF * DM;          // 262144
    size_t w2B = (size_t)DM * FF;          // 262144
    size_t wqB = (size_t)DM * DM;          // 65536 (x2 for hi/lo)
    size_t wbytes = (woB + w1B + w2B + 2 * wqB) * sizeof(u16);   // 1,441,792
    size_t kvbytes = 2 * (size_t)P * DM * sizeof(float);

    if (ws_size >= wbytes + kvbytes && P <= PMAX && B <= 16 && (nrows % MT) == 0) {
        // fully fused MFMA path
        u16* WoB  = (u16*)d_ws;
        u16* W1Bp = WoB + woB;
        u16* W2Bp = W1Bp + w1B;
        u16* WqhB = W2Bp + w2B;
        u16* WqlB = WqhB + wqB;
        float* kbuf = (float*)(WqlB + wqB);
        float* vbuf = kbuf + (size_t)P * DM;

        cvt_kernel<<<(int)((woB + 255) / 256), 256, 0, stream>>>(out_w, WoB, (int)woB);
        cvt_kernel<<<(int)((w1B + 255) / 256), 256, 0, stream>>>(w1, W1Bp, (int)w1B);
        cvt_kernel<<<(int)((w2B + 255) / 256), 256, 0, stream>>>(w2, W2Bp, (int)w2B);
        cvt_hilo_kernel<<<(int)((wqB + 255) / 256), 256, 0, stream>>>(in_w, WqhB, WqlB, (int)wqB);
        kvproj_kernel<<<P, 256, 0, stream>>>(Hg, pidx, in_w, in_b, kbuf, vbuf);
        fused_all_kernel<<<(unsigned)(nrows / MT), 256, 0, stream>>>(
            Hg, WqhB, WqlB, in_b, kbuf, vbuf, assign,
            WoB, out_b, W1Bp, b1, W2Bp, b2, g1, bb1, g2, bb2, out, P, B);
    } else {
        // fallback: R3-proven VALU path (kv only in ws)
        float* kbuf = (float*)d_ws;
        float* vbuf = kbuf + (size_t)P * DM;
        kvproj_kernel<<<P, 256, 0, stream>>>(Hg, pidx, in_w, in_b, kbuf, vbuf);
        attn_fb_kernel<<<dim3(N_GENES, B), 256, 0, stream>>>(
            Hg, kbuf, vbuf, assign, in_w, in_b, out_w, out_b, g1, bb1, out, P);
        ffn_fb_kernel<<<(unsigned)(nrows / 4), 256, 0, stream>>>(
            out, w1, b1, w2, b2, g2, bb2);
    }
}

// Round 3
// 926.947 us; speedup vs baseline: 1.2205x; 1.2205x over previous
//
#include <hip/hip_runtime.h>
#include <math.h>

// Problem constants: N=6000, D=256, H=8, DH=32, P=128, B=16. fp32 in/out (established R3).
#define N_GENES 6000
#define DM 256
#define NH 8
#define DHEAD 32
#define FF 1024
#define PMAX 128
#define MT 32     // rows per block = 2 genes x 16 batches
#define LDP 264   // padded LDS inner dim for u16 arrays
#define LDQ 268   // padded LDS inner dim for f32 arrays

typedef unsigned short u16;
typedef unsigned int u32;
typedef __attribute__((ext_vector_type(8))) short s8bf;  // 8 bf16 in 4 VGPRs
typedef __attribute__((ext_vector_type(4))) float f4;

__device__ __forceinline__ f4 mfma_bf16(s8bf a, s8bf b, f4 c) {
    return __builtin_amdgcn_mfma_f32_16x16x32_bf16(a, b, c, 0, 0, 0);
}

__device__ __forceinline__ float bf2f(u16 u) { return __uint_as_float(((u32)u) << 16); }
__device__ __forceinline__ u16 f2bf(float f) {
    u32 x = __float_as_uint(f);
    return (u16)((x + 0x7fffu + ((x >> 16) & 1u)) >> 16);  // RNE
}
__device__ __forceinline__ float gelu_exact(float x) {
    return 0.5f * x * (1.0f + erff(x * 0.70710678118654752f));
}

// ---------------- fp32 -> bf16 weight conversion ----------------
__global__ __launch_bounds__(256) void cvt_kernel(const float* __restrict__ src,
                                                  u16* __restrict__ dst, int n) {
    int i = blockIdx.x * 256 + threadIdx.x;
    if (i < n) dst[i] = f2bf(src[i]);
}

// ---------------- k/v projection for the P gathered rows (fp32) ----------------
__global__ __launch_bounds__(256) void kvproj_kernel(
    const float* __restrict__ Hg, const int* __restrict__ pidx,
    const float* __restrict__ Win, const float* __restrict__ bin,
    float* __restrict__ kbuf, float* __restrict__ vbuf) {
    __shared__ float xs[DM];
    int p = blockIdx.x, d = threadIdx.x;
    int row = pidx[p];
    xs[d] = Hg[(size_t)row * DM + d];
    __syncthreads();
    const float4* wk = (const float4*)(Win + (size_t)(DM + d) * DM);
    const float4* wv = (const float4*)(Win + (size_t)(2 * DM + d) * DM);
    float ak = bin[DM + d];
    float av = bin[2 * DM + d];
    #pragma unroll 4
    for (int k = 0; k < DM / 4; ++k) {
        float4 a = wk[k], b = wv[k];
        float x0 = xs[4*k], x1 = xs[4*k+1], x2 = xs[4*k+2], x3 = xs[4*k+3];
        ak += a.x * x0 + a.y * x1 + a.z * x2 + a.w * x3;
        av += b.x * x0 + b.y * x1 + b.z * x2 + b.w * x3;
    }
    kbuf[(size_t)p * DM + d] = ak;
    vbuf[(size_t)p * DM + d] = av;
}

// ==== fully fused, 2 genes x 16 batches per block ====
// qproj once per gene (fp32 VALU, exact) -> scores once into LDS -> softmax/ctx ->
// GEMM0 + LN1 + FFN + LN2 (MFMA bf16) -> LDS-staged coalesced out write.
__global__ __launch_bounds__(256, 3) void fused_all_kernel(
    const float* __restrict__ Hg, const float* __restrict__ Win,
    const float* __restrict__ bin,
    const float* __restrict__ kbuf, const float* __restrict__ vbuf,
    const int* __restrict__ assign,
    const u16* __restrict__ WoB, const float* __restrict__ bout,
    const u16* __restrict__ W1B, const float* __restrict__ b1,
    const u16* __restrict__ W2B, const float* __restrict__ b2,
    const float* __restrict__ g1, const float* __restrict__ bb1,
    const float* __restrict__ g2, const float* __restrict__ bb2,
    float* __restrict__ out, int P, int B) {

    __shared__ __align__(16) char reg1_raw[MT * LDQ * 4];   // 34,304 B time-shared region
    __shared__ __align__(16) u16 xb[MT][LDP];               // 16,896 B: ctx(bf16) then x(bf16)
    __shared__ int asg[PMAX];
    __shared__ int startb[16];
    __shared__ int cntb[16];
    __shared__ float hasb[16];

    float* reg1f = (float*)reg1_raw;
    // time-shared layout (early phases, all within first 12.8KB):
    float* qs   = reg1f;               // [16][36] : (g*8+h)*36 + e, padded vs bank 0 pile-up
    float* hrow = reg1f + 16 * 36;     // [2][256] staged gene rows (byte off 2304, 16-aligned)
    float (*sc)[132] = (float(*)[132])(reg1f + 16 * 36 + 2 * DM);  // [16][132] scores
    // later phases reuse whole region:
    float (*sb)[LDQ] = (float(*)[LDQ])reg1_raw;  // GEMM dump fp32
    u16  (*hb)[LDP]  = (u16 (*)[LDP])reg1_raw;   // hidden bf16 (FFN)

    const f4 fzero = {0.f, 0.f, 0.f, 0.f};
    int tid = threadIdx.x;
    int wv = tid >> 6, l = tid & 63;
    int l15 = l & 15, q8 = (l >> 4) * 8, q4 = (l >> 4) * 4;
    int n0 = blockIdx.x * 2;   // 2 genes per block
    // row mapping: r in [0,32): gene gi = r&1, batch b = r>>1

    // ---- P0: stage assignment + the 2 gene rows ----
    if (tid < P) asg[tid] = assign[tid];
    for (int i = tid; i < 2 * DM; i += 256)
        hrow[i] = Hg[(size_t)n0 * DM + i];
    __syncthreads();
    if (tid < B) {
        int s = 0, c = 0;
        for (int p = 0; p < P; ++p) { int a = asg[p]; s += (a < tid); c += (a == tid); }
        startb[tid] = s; cntb[tid] = c; hasb[tid] = c ? 1.f : 0.f;
    }

    // ---- P1: qproj (once per gene, fp32 VALU exact). thread d=tid computes q[g][d]. ----
    {
        const float4* wr = (const float4*)(Win + (size_t)tid * DM);
        float a0 = bin[tid], a1 = a0;
        #pragma unroll 4
        for (int k = 0; k < DM / 4; ++k) {
            float4 w = wr[k];
            float h00 = hrow[4*k], h01 = hrow[4*k+1], h02 = hrow[4*k+2], h03 = hrow[4*k+3];
            float h10 = hrow[DM+4*k], h11 = hrow[DM+4*k+1], h12 = hrow[DM+4*k+2], h13 = hrow[DM+4*k+3];
            a0 += w.x * h00 + w.y * h01 + w.z * h02 + w.w * h03;
            a1 += w.x * h10 + w.y * h11 + w.z * h12 + w.w * h13;
        }
        int h = tid >> 5, e = tid & 31;
        qs[(h) * 36 + e]     = a0 * 0.17677669529663687f;   // g=0
        qs[(8 + h) * 36 + e] = a1 * 0.17677669529663687f;   // g=1
    }
    __syncthreads();

    // ---- P2a: all scores once. idx -> gh = idx&15 (g=gh>>3,h=gh&7), p = idx>>4. ----
    for (int idx = tid; idx < 16 * P; idx += 256) {
        int gh = idx & 15, p = idx >> 4;
        const float* qp = qs + gh * 36;
        const float4* kr = (const float4*)(kbuf + (size_t)p * DM + (gh & 7) * DHEAD);
        float d = 0.f;
        #pragma unroll
        for (int e = 0; e < 8; ++e) {
            float4 kv = kr[e];
            d += qp[4*e] * kv.x + qp[4*e+1] * kv.y + qp[4*e+2] * kv.z + qp[4*e+3] * kv.w;
        }
        sc[gh][p] = d;
    }
    __syncthreads();

    // ---- P2b: softmax + ctx per (row r, head h); scores read from LDS (computed once). ----
    {
        int r = tid >> 3, h = tid & 7;
        int gi = r & 1, b = r >> 1;
        int s = startb[b], c = cntb[b];
        float4 cx[8];
        #pragma unroll
        for (int e = 0; e < 8; ++e) cx[e] = make_float4(0.f, 0.f, 0.f, 0.f);
        if (c > 0) {
            const float* scp = sc[gi * 8 + h];
            float m = -INFINITY;
            for (int i = 0; i < c; ++i) m = fmaxf(m, scp[s + i]);
            float sum = 0.f;
            const float* vb0 = vbuf + h * DHEAD;
            for (int i = 0; i < c; ++i) {
                float w = __expf(scp[s + i] - m);
                sum += w;
                const float4* vr = (const float4*)(vb0 + (size_t)(s + i) * DM);
                #pragma unroll
                for (int e = 0; e < 8; ++e) {
                    float4 vvv = vr[e];
                    cx[e].x += w * vvv.x; cx[e].y += w * vvv.y;
                    cx[e].z += w * vvv.z; cx[e].w += w * vvv.w;
                }
            }
            float inv = 1.0f / sum;
            #pragma unroll
            for (int e = 0; e < 8; ++e) {
                cx[e].x *= inv; cx[e].y *= inv; cx[e].z *= inv; cx[e].w *= inv;
            }
        }
        // ctx -> xb as bf16 (feeds GEMM0 A-frags; zeros for empty batch)
        u16* xrow = &xb[r][h * DHEAD];
        #pragma unroll
        for (int e = 0; e < 8; ++e) {
            *(u32*)(xrow + 4 * e)     = (u32)f2bf(cx[e].x) | ((u32)f2bf(cx[e].y) << 16);
            *(u32*)(xrow + 4 * e + 2) = (u32)f2bf(cx[e].z) | ((u32)f2bf(cx[e].w) << 16);
        }
    }
    __syncthreads();

    // ---- P3: GEMM0: attn_raw = ctx @ Wout^T -> sb (early region dead) ----
    {
        f4 acc[2][4] = {fzero, fzero, fzero, fzero, fzero, fzero, fzero, fzero};
        for (int k0 = 0; k0 < DM; k0 += 32) {
            s8bf a0 = *(const s8bf*)&xb[l15][k0 + q8];
            s8bf a1 = *(const s8bf*)&xb[16 + l15][k0 + q8];
            #pragma unroll
            for (int nt = 0; nt < 4; ++nt) {
                int nn = wv * 64 + nt * 16 + l15;
                s8bf wfrag = *(const s8bf*)&WoB[(size_t)nn * DM + k0 + q8];
                acc[0][nt] = mfma_bf16(a0, wfrag, acc[0][nt]);
                acc[1][nt] = mfma_bf16(a1, wfrag, acc[1][nt]);
            }
        }
        #pragma unroll
        for (int mt = 0; mt < 2; ++mt)
            #pragma unroll
            for (int nt = 0; nt < 4; ++nt)
                #pragma unroll
                for (int r = 0; r < 4; ++r)
                    sb[mt * 16 + q4 + r][wv * 64 + nt * 16 + l15] = acc[mt][nt][r];
    }
    __syncthreads();

    // ---- LN1: t = H + has*(sb + bout); x -> xb (bf16) ----
    {
        int r = tid >> 3, cg = (tid & 7) * 32;
        int gi = r & 1, b = r >> 1;
        float has = hasb[b];
        const float* hp = Hg + (size_t)(n0 + gi) * DM + cg;
        const float* bo = bout + cg;
        float tv[32];
        float sum = 0.f;
        #pragma unroll
        for (int j = 0; j < 32; j += 4) {
            float4 hv = *(const float4*)(hp + j);
            float4 bv = *(const float4*)(bo + j);
            float t0 = hv.x + has * (sb[r][cg + j]     + bv.x);
            float t1 = hv.y + has * (sb[r][cg + j + 1] + bv.y);
            float t2 = hv.z + has * (sb[r][cg + j + 2] + bv.z);
            float t3 = hv.w + has * (sb[r][cg + j + 3] + bv.w);
            tv[j] = t0; tv[j+1] = t1; tv[j+2] = t2; tv[j+3] = t3;
            sum += t0 + t1 + t2 + t3;
        }
        sum += __shfl_xor(sum, 1, 8); sum += __shfl_xor(sum, 2, 8); sum += __shfl_xor(sum, 4, 8);
        float mu = sum * (1.0f / DM);
        float vs = 0.f;
        #pragma unroll
        for (int j = 0; j < 32; ++j) { float dd = tv[j] - mu; vs += dd * dd; }
        vs += __shfl_xor(vs, 1, 8); vs += __shfl_xor(vs, 2, 8); vs += __shfl_xor(vs, 4, 8);
        float rs = rsqrtf(vs * (1.0f / DM) + 1e-5f);
        #pragma unroll
        for (int j = 0; j < 32; j += 2) {
            float x0 = (tv[j]     - mu) * rs * g1[cg + j]     + bb1[cg + j];
            float x1 = (tv[j + 1] - mu) * rs * g1[cg + j + 1] + bb1[cg + j + 1];
            *(u32*)&xb[r][cg + j] = (u32)f2bf(x0) | ((u32)f2bf(x1) << 16);
        }
    }
    __syncthreads();

    // ---- P4: FFN: GEMM1 (+b1, GELU) chunked 4x256 -> hb; GEMM2 accumulates ----
    f4 acc2[2][4] = {fzero, fzero, fzero, fzero, fzero, fzero, fzero, fzero};
    for (int ch = 0; ch < 4; ++ch) {
        f4 acc1[2][4] = {fzero, fzero, fzero, fzero, fzero, fzero, fzero, fzero};
        for (int k0 = 0; k0 < DM; k0 += 32) {
            s8bf a0 = *(const s8bf*)&xb[l15][k0 + q8];
            s8bf a1 = *(const s8bf*)&xb[16 + l15][k0 + q8];
            #pragma unroll
            for (int nt = 0; nt < 4; ++nt) {
                int nn = ch * 256 + wv * 64 + nt * 16 + l15;
                s8bf wfrag = *(const s8bf*)&W1B[(size_t)nn * DM + k0 + q8];
                acc1[0][nt] = mfma_bf16(a0, wfrag, acc1[0][nt]);
                acc1[1][nt] = mfma_bf16(a1, wfrag, acc1[1][nt]);
            }
        }
        #pragma unroll
        for (int nt = 0; nt < 4; ++nt) {
            int cl = wv * 64 + nt * 16 + l15;
            float bb = b1[ch * 256 + cl];
            #pragma unroll
            for (int mt = 0; mt < 2; ++mt)
                #pragma unroll
                for (int r = 0; r < 4; ++r)
                    hb[mt * 16 + q4 + r][cl] = f2bf(gelu_exact(acc1[mt][nt][r] + bb));
        }
        __syncthreads();
        for (int k0 = 0; k0 < DM; k0 += 32) {
            s8bf a0 = *(const s8bf*)&hb[l15][k0 + q8];
            s8bf a1 = *(const s8bf*)&hb[16 + l15][k0 + q8];
            #pragma unroll
            for (int nt = 0; nt < 4; ++nt) {
                int nn = wv * 64 + nt * 16 + l15;
                s8bf wfrag = *(const s8bf*)&W2B[(size_t)nn * FF + ch * 256 + k0 + q8];
                acc2[0][nt] = mfma_bf16(a0, wfrag, acc2[0][nt]);
                acc2[1][nt] = mfma_bf16(a1, wfrag, acc2[1][nt]);
            }
        }
        __syncthreads();
    }
    #pragma unroll
    for (int mt = 0; mt < 2; ++mt)
        #pragma unroll
        for (int nt = 0; nt < 4; ++nt)
            #pragma unroll
            for (int r = 0; r < 4; ++r)
                sb[mt * 16 + q4 + r][wv * 64 + nt * 16 + l15] = acc2[mt][nt][r];
    __syncthreads();

    // ---- LN2: t = x + (ffn + b2); y staged back into sb, then coalesced write ----
    {
        int r = tid >> 3, cg = (tid & 7) * 32;
        const float* bp = b2 + cg;
        float tv[32];
        float sum = 0.f;
        #pragma unroll
        for (int j = 0; j < 32; j += 4) {
            float4 bv = *(const float4*)(bp + j);
            float t0 = bf2f(xb[r][cg + j])     + sb[r][cg + j]     + bv.x;
            float t1 = bf2f(xb[r][cg + j + 1]) + sb[r][cg + j + 1] + bv.y;
            float t2 = bf2f(xb[r][cg + j + 2]) + sb[r][cg + j + 2] + bv.z;
            float t3 = bf2f(xb[r][cg + j + 3]) + sb[r][cg + j + 3] + bv.w;
            tv[j] = t0; tv[j+1] = t1; tv[j+2] = t2; tv[j+3] = t3;
            sum += t0 + t1 + t2 + t3;
        }
        sum += __shfl_xor(sum, 1, 8); sum += __shfl_xor(sum, 2, 8); sum += __shfl_xor(sum, 4, 8);
        float mu = sum * (1.0f / DM);
        float vs = 0.f;
        #pragma unroll
        for (int j = 0; j < 32; ++j) { float dd = tv[j] - mu; vs += dd * dd; }
        vs += __shfl_xor(vs, 1, 8); vs += __shfl_xor(vs, 2, 8); vs += __shfl_xor(vs, 4, 8);
        float rs = rsqrtf(vs * (1.0f / DM) + 1e-5f);
        #pragma unroll
        for (int j = 0; j < 32; ++j)
            sb[r][cg + j] = (tv[j] - mu) * rs * g2[cg + j] + bb2[cg + j];
    }
    __syncthreads();
    // coalesced write: one full 1KB row chunk per wave-instruction (full 128B lines)
    for (int i = tid; i < MT * 64; i += 256) {
        int r = i >> 6, c4 = (i & 63) << 2;
        size_t gr = (size_t)(r >> 1) * N_GENES + (size_t)(n0 + (r & 1));
        *(float4*)(out + gr * DM + c4) = *(const float4*)&sb[r][c4];
    }
}

// ================= fallback path (ws too small for weight staging): R3-proven VALU =================
__global__ __launch_bounds__(256) void attn_fb_kernel(
    const float* __restrict__ Hg, const float* __restrict__ kbuf, const float* __restrict__ vbuf,
    const int* __restrict__ assign, const float* __restrict__ Win, const float* __restrict__ bin,
    const float* __restrict__ Wout, const float* __restrict__ bout,
    const float* __restrict__ ln1g, const float* __restrict__ ln1b,
    float* __restrict__ xout, int P) {
    __shared__ float qs[DM];
    __shared__ float hrow[DM];
    __shared__ float sc[NH][PMAX + 1];
    __shared__ float ctxs[DM];
    __shared__ int asg[PMAX];
    __shared__ float red[4];

    int n = blockIdx.x, b = blockIdx.y, tid = threadIdx.x;
    if (tid < P) asg[tid] = assign[tid];
    hrow[tid] = Hg[(size_t)n * DM + tid];
    __syncthreads();
    {
        const float4* wr = (const float4*)(Win + (size_t)tid * DM);
        float acc = bin[tid];
        #pragma unroll 4
        for (int k = 0; k < DM / 4; ++k) {
            float4 w = wr[k];
            acc += w.x * hrow[4*k] + w.y * hrow[4*k+1] + w.z * hrow[4*k+2] + w.w * hrow[4*k+3];
        }
        qs[tid] = acc * 0.17677669529663687f;
        __syncthreads();
    }
    int start = 0, cnt = 0;
    for (int p = 0; p < P; ++p) { int a = asg[p]; start += (a < b); cnt += (a == b); }
    for (int idx = tid; idx < NH * cnt; idx += 256) {
        int h = idx & (NH - 1), pl = idx >> 3;
        const float* krow = kbuf + (size_t)(start + pl) * DM + h * DHEAD;
        const float* qh = qs + h * DHEAD;
        float acc = 0.f;
        #pragma unroll
        for (int e = 0; e < DHEAD; ++e) acc += qh[e] * krow[e];
        sc[h][pl] = acc;
    }
    __syncthreads();
    if (cnt > 0) {
        int h = tid >> 5, ll = tid & 31;
        float m = -INFINITY;
        for (int p = ll; p < cnt; p += 32) m = fmaxf(m, sc[h][p]);
        #pragma unroll
        for (int off = 16; off > 0; off >>= 1) m = fmaxf(m, __shfl_xor(m, off, 32));
        float s = 0.f;
        for (int p = ll; p < cnt; p += 32) { float e = __expf(sc[h][p] - m); sc[h][p] = e; s += e; }
        #pragma unroll
        for (int off = 16; off > 0; off >>= 1) s += __shfl_xor(s, off, 32);
        float inv = 1.0f / s;
        for (int p = ll; p < cnt; p += 32) sc[h][p] *= inv;
    }
    __syncthreads();
    {
        int hh = tid >> 5, e = tid & 31;
        float acc = 0.f;
        for (int p = 0; p < cnt; ++p)
            acc += sc[hh][p] * vbuf[(size_t)(start + p) * DM + hh * DHEAD + e];
        ctxs[tid] = acc;
    }
    __syncthreads();
    float ao = 0.f;
    if (cnt > 0) {
        ao = bout[tid];
        const float4* wr = (const float4*)(Wout + (size_t)tid * DM);
        #pragma unroll 4
        for (int k = 0; k < DM / 4; ++k) {
            float4 w = wr[k];
            ao += w.x * ctxs[4*k] + w.y * ctxs[4*k+1] + w.z * ctxs[4*k+2] + w.w * ctxs[4*k+3];
        }
    }
    float t = hrow[tid] + ao;
    {
        float v = t;
        #pragma unroll
        for (int off = 32; off > 0; off >>= 1) v += __shfl_down(v, off, 64);
        if ((tid & 63) == 0) red[tid >> 6] = v;
        __syncthreads();
        float mu = (red[0] + red[1] + red[2] + red[3]) * (1.0f / DM);
        __syncthreads();
        float dv = t - mu, v2 = dv * dv;
        #pragma unroll
        for (int off = 32; off > 0; off >>= 1) v2 += __shfl_down(v2, off, 64);
        if ((tid & 63) == 0) red[tid >> 6] = v2;
        __syncthreads();
        float var = (red[0] + red[1] + red[2] + red[3]) * (1.0f / DM);
        float xv = dv * rsqrtf(var + 1e-5f) * ln1g[tid] + ln1b[tid];
        xout[((size_t)b * N_GENES + n) * DM + tid] = xv;
    }
}

__global__ __launch_bounds__(256) void ffn_fb_kernel(
    float* __restrict__ xio, const float* __restrict__ W1, const float* __restrict__ b1,
    const float* __restrict__ W2, const float* __restrict__ b2,
    const float* __restrict__ ln2g, const float* __restrict__ ln2b) {
    __shared__ float xs[4][DM];
    __shared__ float hs[4][FF];
    __shared__ float red[4];
    int tid = threadIdx.x;
    size_t row0 = (size_t)blockIdx.x * 4;
    for (int i = tid; i < 4 * DM; i += 256)
        ((float*)xs)[i] = xio[row0 * DM + i];
    __syncthreads();
    for (int oi = 0; oi < FF / 256; ++oi) {
        int o = oi * 256 + tid;
        float bb = b1[o];
        float a0 = bb, a1 = bb, a2 = bb, a3 = bb;
        const float4* wr = (const float4*)(W1 + (size_t)o * DM);
        #pragma unroll 2
        for (int k = 0; k < DM / 4; ++k) {
            float4 w = wr[k];
            a0 += w.x * xs[0][4*k] + w.y * xs[0][4*k+1] + w.z * xs[0][4*k+2] + w.w * xs[0][4*k+3];
            a1 += w.x * xs[1][4*k] + w.y * xs[1][4*k+1] + w.z * xs[1][4*k+2] + w.w * xs[1][4*k+3];
            a2 += w.x * xs[2][4*k] + w.y * xs[2][4*k+1] + w.z * xs[2][4*k+2] + w.w * xs[2][4*k+3];
            a3 += w.x * xs[3][4*k] + w.y * xs[3][4*k+1] + w.z * xs[3][4*k+2] + w.w * xs[3][4*k+3];
        }
        hs[0][o] = gelu_exact(a0); hs[1][o] = gelu_exact(a1);
        hs[2][o] = gelu_exact(a2); hs[3][o] = gelu_exact(a3);
    }
    __syncthreads();
    int d = tid;
    float bb2 = b2[d];
    float c0 = bb2, c1 = bb2, c2 = bb2, c3 = bb2;
    const float4* wr = (const float4*)(W2 + (size_t)d * FF);
    #pragma unroll 2
    for (int k = 0; k < FF / 4; ++k) {
        float4 w = wr[k];
        c0 += w.x * hs[0][4*k] + w.y * hs[0][4*k+1] + w.z * hs[0][4*k+2] + w.w * hs[0][4*k+3];
        c1 += w.x * hs[1][4*k] + w.y * hs[1][4*k+1] + w.z * hs[1][4*k+2] + w.w * hs[1][4*k+3];
        c2 += w.x * hs[2][4*k] + w.y * hs[2][4*k+1] + w.z * hs[2][4*k+2] + w.w * hs[2][4*k+3];
        c3 += w.x * hs[3][4*k] + w.y * hs[3][4*k+1] + w.z * hs[3][4*k+2] + w.w * hs[3][4*k+3];
    }
    float cr[4] = {c0, c1, c2, c3};
    float g = ln2g[d], bln = ln2b[d];
    #pragma unroll
    for (int r = 0; r < 4; ++r) {
        float t = cr[r] + xs[r][d];
        float v = t;
        #pragma unroll
        for (int off = 32; off > 0; off >>= 1) v += __shfl_down(v, off, 64);
        if ((tid & 63) == 0) red[tid >> 6] = v;
        __syncthreads();
        float mu = (red[0] + red[1] + red[2] + red[3]) * (1.0f / DM);
        __syncthreads();
        float dv = t - mu, v2 = dv * dv;
        #pragma unroll
        for (int off = 32; off > 0; off >>= 1) v2 += __shfl_down(v2, off, 64);
        if ((tid & 63) == 0) red[tid >> 6] = v2;
        __syncthreads();
        float var = (red[0] + red[1] + red[2] + red[3]) * (1.0f / DM);
        float y = dv * rsqrtf(var + 1e-5f) * g + bln;
        xio[(row0 + r) * DM + d] = y;
        __syncthreads();
    }
}

extern "C" void kernel_launch(void* const* d_in, const int* in_sizes, int n_in,
                              void* d_out, int out_size, void* d_ws, size_t ws_size,
                              hipStream_t stream) {
    const float* Hg   = (const float*)d_in[0];
    const int* pidx   = (const int*)d_in[1];
    const int* assign = (const int*)d_in[2];
    const float* in_w = (const float*)d_in[4];
    const float* in_b = (const float*)d_in[5];
    const float* out_w= (const float*)d_in[6];
    const float* out_b= (const float*)d_in[7];
    const float* w1   = (const float*)d_in[8];
    const float* b1   = (const float*)d_in[9];
    const float* w2   = (const float*)d_in[10];
    const float* b2   = (const float*)d_in[11];
    const float* g1   = (const float*)d_in[12];
    const float* bb1  = (const float*)d_in[13];
    const float* g2   = (const float*)d_in[14];
    const float* bb2  = (const float*)d_in[15];

    int P = in_sizes[1];
    int B = out_size / (N_GENES * DM);
    size_t nrows = (size_t)B * N_GENES;
    float* out = (float*)d_out;

    size_t woB = (size_t)DM * DM;          // 65536
    size_t w1B = (size_t)FF * DM;          // 262144
    size_t w2B = (size_t)DM * FF;          // 262144
    size_t wbytes = (woB + w1B + w2B) * sizeof(u16);   // 1,179,648
    size_t kvbytes = 2 * (size_t)P * DM * sizeof(float);

    if (ws_size >= wbytes + kvbytes && P <= PMAX && B == 16 && (N_GENES % 2) == 0) {
        // fully fused MFMA path (2 genes x 16 batches per block)
        u16* WoB  = (u16*)d_ws;
        u16* W1Bp = WoB + woB;
        u16* W2Bp = W1Bp + w1B;
        float* kbuf = (float*)(W2Bp + w2B);
        float* vbuf = kbuf + (size_t)P * DM;

        cvt_kernel<<<(int)((woB + 255) / 256), 256, 0, stream>>>(out_w, WoB, (int)woB);
        cvt_kernel<<<(int)((w1B + 255) / 256), 256, 0, stream>>>(w1, W1Bp, (int)w1B);
        cvt_kernel<<<(int)((w2B + 255) / 256), 256, 0, stream>>>(w2, W2Bp, (int)w2B);
        kvproj_kernel<<<P, 256, 0, stream>>>(Hg, pidx, in_w, in_b, kbuf, vbuf);
        fused_all_kernel<<<N_GENES / 2, 256, 0, stream>>>(
            Hg, in_w, in_b, kbuf, vbuf, assign,
            WoB, out_b, W1Bp, b1, W2Bp, b2, g1, bb1, g2, bb2, out, P, B);
    } else {
        // fallback: R3-proven VALU path (kv only in ws)
        float* kbuf = (float*)d_ws;
        float* vbuf = kbuf + (size_t)P * DM;
        kvproj_kernel<<<P, 256, 0, stream>>>(Hg, pidx, in_w, in_b, kbuf, vbuf);
        attn_fb_kernel<<<dim3(N_GENES, B), 256, 0, stream>>>(
            Hg, kbuf, vbuf, assign, in_w, in_b, out_w, out_b, g1, bb1, out, P);
        ffn_fb_kernel<<<(unsigned)(nrows / 4), 256, 0, stream>>>(
            out, w1, b1, w2, b2, g2, bb2);
    }
}

// Round 4
// 823.329 us; speedup vs baseline: 1.3741x; 1.1259x over previous
//
#include <hip/hip_runtime.h>
#include <math.h>

// Problem constants: N=6000, D=256, H=8, DH=32, P=128, B=16. fp32 in/out (established R3).
#define N_GENES 6000
#define DM 256
#define NH 8
#define DHEAD 32
#define FF 1024
#define PMAX 128
#define MT 32     // rows per block = 2 genes x 16 batches
#define LDP 264   // padded LDS inner dim for u16 arrays (row stride 528B, 16B-aligned)
#define LDS16 268 // padded inner dim for the 16-row f32 bounce (stride 1072B)

typedef unsigned short u16;
typedef unsigned int u32;
typedef __attribute__((ext_vector_type(8))) short s8bf;  // 8 bf16 in 4 VGPRs
typedef __attribute__((ext_vector_type(4))) float f4;

__device__ __forceinline__ f4 mfma_bf16(s8bf a, s8bf b, f4 c) {
    return __builtin_amdgcn_mfma_f32_16x16x32_bf16(a, b, c, 0, 0, 0);
}

__device__ __forceinline__ float bf2f(u16 u) { return __uint_as_float(((u32)u) << 16); }
__device__ __forceinline__ u16 f2bf(float f) {
    u32 x = __float_as_uint(f);
    return (u16)((x + 0x7fffu + ((x >> 16) & 1u)) >> 16);  // RNE
}
__device__ __forceinline__ float gelu_exact(float x) {
    return 0.5f * x * (1.0f + erff(x * 0.70710678118654752f));
}

// ---------------- fp32 -> bf16 weight conversion ----------------
__global__ __launch_bounds__(256) void cvt_kernel(const float* __restrict__ src,
                                                  u16* __restrict__ dst, int n) {
    int i = blockIdx.x * 256 + threadIdx.x;
    if (i < n) dst[i] = f2bf(src[i]);
}

// ---------------- k/v projection for the P gathered rows (fp32) ----------------
__global__ __launch_bounds__(256) void kvproj_kernel(
    const float* __restrict__ Hg, const int* __restrict__ pidx,
    const float* __restrict__ Win, const float* __restrict__ bin,
    float* __restrict__ kbuf, float* __restrict__ vbuf) {
    __shared__ float xs[DM];
    int p = blockIdx.x, d = threadIdx.x;
    int row = pidx[p];
    xs[d] = Hg[(size_t)row * DM + d];
    __syncthreads();
    const float4* wk = (const float4*)(Win + (size_t)(DM + d) * DM);
    const float4* wv = (const float4*)(Win + (size_t)(2 * DM + d) * DM);
    float ak = bin[DM + d];
    float av = bin[2 * DM + d];
    #pragma unroll 4
    for (int k = 0; k < DM / 4; ++k) {
        float4 a = wk[k], b = wv[k];
        float x0 = xs[4*k], x1 = xs[4*k+1], x2 = xs[4*k+2], x3 = xs[4*k+3];
        ak += a.x * x0 + a.y * x1 + a.z * x2 + a.w * x3;
        av += b.x * x0 + b.y * x1 + b.z * x2 + b.w * x3;
    }
    kbuf[(size_t)p * DM + d] = ak;
    vbuf[(size_t)p * DM + d] = av;
}

// ==== fully fused, 2 genes x 16 batches per block, 512 threads / 8 waves ====
// LDS ~35KB -> 4 blocks/CU (LDS-wise); launch_bounds(512,6) -> >=24 waves/CU.
// Epilogues (GEMM dumps + LayerNorms) run in two 16-row halves through a 17KB bounce.
__global__ __launch_bounds__(512, 6) void fused_all_kernel(
    const float* __restrict__ Hg, const float* __restrict__ Win,
    const float* __restrict__ bin,
    const float* __restrict__ kbuf, const float* __restrict__ vbuf,
    const int* __restrict__ assign,
    const u16* __restrict__ WoB, const float* __restrict__ bout,
    const u16* __restrict__ W1B, const float* __restrict__ b1,
    const u16* __restrict__ W2B, const float* __restrict__ b2,
    const float* __restrict__ g1, const float* __restrict__ bb1,
    const float* __restrict__ g2, const float* __restrict__ bb2,
    float* __restrict__ out, int P, int B) {

    __shared__ __align__(16) u16 xb[MT][LDP];        // 16,896 B: ctx(bf16) then x(bf16)
    __shared__ __align__(16) char reg2_raw[16 * LDS16 * 4];  // 17,152 B time-shared
    __shared__ int asg[PMAX];
    __shared__ int startb[16];
    __shared__ int cntb[16];
    __shared__ float hasb[16];

    float* reg2f = (float*)reg2_raw;
    // early-phase layout (all within 16,896 B):
    float* qs   = reg2f;                               // [16][36]  (g*8+h)*36+e
    float* hrow = reg2f + 576;                         // [2][256]
    float (*sc)[132] = (float(*)[132])(reg2f + 1088);  // [16][132] scores
    float* ps   = reg2f + 3200;                        // [2 genes][2 kh][256] qproj partials
    // later phases:
    float (*sb16)[LDS16] = (float(*)[LDS16])reg2_raw;  // [16][268] f32 GEMM dump (half rows)
    u16  (*hb)[LDP]      = (u16 (*)[LDP])reg2_raw;     // [32][264] bf16 hidden chunk

    const f4 fzero = {0.f, 0.f, 0.f, 0.f};
    int tid = threadIdx.x;
    int w = tid >> 6, l = tid & 63;
    int l15 = l & 15, q8 = (l >> 4) * 8, q4 = (l >> 4) * 4;
    int n0 = blockIdx.x * 2;   // 2 genes per block
    // row mapping: r in [0,32): gene gi = r&1, batch b = r>>1

    // ---- P0: stage assignment + the 2 gene rows ----
    if (tid < P) asg[tid] = assign[tid];
    hrow[tid] = Hg[(size_t)n0 * DM + tid];   // 512 threads = 512 floats = 2 rows
    __syncthreads();
    if (tid < B) {
        int s = 0, c = 0;
        for (int p = 0; p < P; ++p) { int a = asg[p]; s += (a < tid); c += (a == tid); }
        startb[tid] = s; cntb[tid] = c; hasb[tid] = c ? 1.f : 0.f;
    }

    // ---- P1: qproj split-k. thread (d = tid&255, kh = tid>>8) does half the K range ----
    {
        int d = tid & 255, kh = tid >> 8;
        const float4* wr = (const float4*)(Win + (size_t)d * DM + kh * 128);
        const float* h0 = hrow + kh * 128;
        const float* h1 = hrow + 256 + kh * 128;
        float a0 = 0.f, a1 = 0.f;
        #pragma unroll 4
        for (int k = 0; k < 32; ++k) {
            float4 ww = wr[k];
            a0 += ww.x * h0[4*k] + ww.y * h0[4*k+1] + ww.z * h0[4*k+2] + ww.w * h0[4*k+3];
            a1 += ww.x * h1[4*k] + ww.y * h1[4*k+1] + ww.z * h1[4*k+2] + ww.w * h1[4*k+3];
        }
        ps[kh * 256 + d] = a0;
        ps[512 + kh * 256 + d] = a1;
    }
    __syncthreads();
    {
        int g = tid >> 8, d = tid & 255;
        float q = (ps[g * 512 + d] + ps[g * 512 + 256 + d] + bin[d]) * 0.17677669529663687f;
        qs[(g * 8 + (d >> 5)) * 36 + (d & 31)] = q;
    }
    __syncthreads();

    // ---- P2a: all scores once. idx -> gh = idx&15 (g=gh>>3,h=gh&7), p = idx>>4. ----
    for (int idx = tid; idx < 16 * P; idx += 512) {
        int gh = idx & 15, p = idx >> 4;
        const float* qp = qs + gh * 36;
        const float4* kr = (const float4*)(kbuf + (size_t)p * DM + (gh & 7) * DHEAD);
        float d = 0.f;
        #pragma unroll
        for (int e = 0; e < 8; ++e) {
            float4 kv = kr[e];
            d += qp[4*e] * kv.x + qp[4*e+1] * kv.y + qp[4*e+2] * kv.z + qp[4*e+3] * kv.w;
        }
        sc[gh][p] = d;
    }
    __syncthreads();

    // ---- P2b: softmax + ctx per (row r, head h); 256 tasks on waves 0-3. ----
    if (tid < 256) {
        int r = tid >> 3, h = tid & 7;
        int gi = r & 1, b = r >> 1;
        int s = startb[b], c = cntb[b];
        float4 cx[8];
        #pragma unroll
        for (int e = 0; e < 8; ++e) cx[e] = make_float4(0.f, 0.f, 0.f, 0.f);
        if (c > 0) {
            const float* scp = sc[gi * 8 + h];
            float m = -INFINITY;
            for (int i = 0; i < c; ++i) m = fmaxf(m, scp[s + i]);
            float sum = 0.f;
            const float* vb0 = vbuf + h * DHEAD;
            for (int i = 0; i < c; ++i) {
                float wgt = __expf(scp[s + i] - m);
                sum += wgt;
                const float4* vr = (const float4*)(vb0 + (size_t)(s + i) * DM);
                #pragma unroll
                for (int e = 0; e < 8; ++e) {
                    float4 vvv = vr[e];
                    cx[e].x += wgt * vvv.x; cx[e].y += wgt * vvv.y;
                    cx[e].z += wgt * vvv.z; cx[e].w += wgt * vvv.w;
                }
            }
            float inv = 1.0f / sum;
            #pragma unroll
            for (int e = 0; e < 8; ++e) {
                cx[e].x *= inv; cx[e].y *= inv; cx[e].z *= inv; cx[e].w *= inv;
            }
        }
        u16* xrow = &xb[r][h * DHEAD];
        #pragma unroll
        for (int e = 0; e < 8; ++e) {
            *(u32*)(xrow + 4 * e)     = (u32)f2bf(cx[e].x) | ((u32)f2bf(cx[e].y) << 16);
            *(u32*)(xrow + 4 * e + 2) = (u32)f2bf(cx[e].z) | ((u32)f2bf(cx[e].w) << 16);
        }
    }
    __syncthreads();

    // ---- P3: GEMM0: attn_raw = ctx @ Wout^T; each wave: 2 nt cols x 2 mt row-halves ----
    f4 g0a[2][2] = {fzero, fzero, fzero, fzero};
    {
        const u16* pw0 = WoB + (size_t)(w * 32 + l15) * DM;
        const u16* pw1 = pw0 + 16 * DM;
        #pragma unroll 4
        for (int k0 = 0; k0 < DM; k0 += 32) {
            s8bf a0 = *(const s8bf*)&xb[l15][k0 + q8];
            s8bf a1 = *(const s8bf*)&xb[16 + l15][k0 + q8];
            s8bf b0 = *(const s8bf*)(pw0 + k0 + q8);
            s8bf b1 = *(const s8bf*)(pw1 + k0 + q8);
            g0a[0][0] = mfma_bf16(a0, b0, g0a[0][0]);
            g0a[1][0] = mfma_bf16(a1, b0, g0a[1][0]);
            g0a[0][1] = mfma_bf16(a0, b1, g0a[0][1]);
            g0a[1][1] = mfma_bf16(a1, b1, g0a[1][1]);
        }
    }
    // epilogue halves: dump -> barrier -> LN1(half) -> barrier
    auto ln1_half = [&](f4 an0, f4 an1, int hf) {
        {
            int cl = w * 32 + l15;
            #pragma unroll
            for (int r = 0; r < 4; ++r) {
                sb16[q4 + r][cl] = an0[r];
                sb16[q4 + r][cl + 16] = an1[r];
            }
        }
        __syncthreads();
        {
            int r16 = tid >> 5, c8 = (tid & 31) * 8;
            int row = hf * 16 + r16;
            int gi = row & 1, b = row >> 1;
            float has = hasb[b];
            const float* hp = Hg + (size_t)(n0 + gi) * DM + c8;
            const float* bo = bout + c8;
            float tv[8];
            float sum = 0.f;
            #pragma unroll
            for (int j = 0; j < 8; j += 4) {
                float4 hv = *(const float4*)(hp + j);
                float4 bv = *(const float4*)(bo + j);
                float t0 = hv.x + has * (sb16[r16][c8 + j]     + bv.x);
                float t1 = hv.y + has * (sb16[r16][c8 + j + 1] + bv.y);
                float t2 = hv.z + has * (sb16[r16][c8 + j + 2] + bv.z);
                float t3 = hv.w + has * (sb16[r16][c8 + j + 3] + bv.w);
                tv[j] = t0; tv[j+1] = t1; tv[j+2] = t2; tv[j+3] = t3;
                sum += t0 + t1 + t2 + t3;
            }
            sum += __shfl_xor(sum, 1, 32); sum += __shfl_xor(sum, 2, 32);
            sum += __shfl_xor(sum, 4, 32); sum += __shfl_xor(sum, 8, 32);
            sum += __shfl_xor(sum, 16, 32);
            float mu = sum * (1.0f / DM);
            float vs = 0.f;
            #pragma unroll
            for (int j = 0; j < 8; ++j) { float dd = tv[j] - mu; vs += dd * dd; }
            vs += __shfl_xor(vs, 1, 32); vs += __shfl_xor(vs, 2, 32);
            vs += __shfl_xor(vs, 4, 32); vs += __shfl_xor(vs, 8, 32);
            vs += __shfl_xor(vs, 16, 32);
            float rs = rsqrtf(vs * (1.0f / DM) + 1e-5f);
            #pragma unroll
            for (int j = 0; j < 8; j += 2) {
                float x0 = (tv[j]     - mu) * rs * g1[c8 + j]     + bb1[c8 + j];
                float x1 = (tv[j + 1] - mu) * rs * g1[c8 + j + 1] + bb1[c8 + j + 1];
                *(u32*)&xb[row][c8 + j] = (u32)f2bf(x0) | ((u32)f2bf(x1) << 16);
            }
        }
        __syncthreads();
    };
    ln1_half(g0a[0][0], g0a[0][1], 0);
    ln1_half(g0a[1][0], g0a[1][1], 1);

    // ---- P4: FFN: GEMM1 (+b1, GELU) chunked 4x256 -> hb; GEMM2 accumulates ----
    f4 acc2[2][2] = {fzero, fzero, fzero, fzero};
    for (int ch = 0; ch < 4; ++ch) {
        f4 acc1[2][2] = {fzero, fzero, fzero, fzero};
        {
            const u16* pw0 = W1B + (size_t)(ch * 256 + w * 32 + l15) * DM;
            const u16* pw1 = pw0 + 16 * DM;
            #pragma unroll 4
            for (int k0 = 0; k0 < DM; k0 += 32) {
                s8bf a0 = *(const s8bf*)&xb[l15][k0 + q8];
                s8bf a1 = *(const s8bf*)&xb[16 + l15][k0 + q8];
                s8bf b0 = *(const s8bf*)(pw0 + k0 + q8);
                s8bf b1 = *(const s8bf*)(pw1 + k0 + q8);
                acc1[0][0] = mfma_bf16(a0, b0, acc1[0][0]);
                acc1[1][0] = mfma_bf16(a1, b0, acc1[1][0]);
                acc1[0][1] = mfma_bf16(a0, b1, acc1[0][1]);
                acc1[1][1] = mfma_bf16(a1, b1, acc1[1][1]);
            }
        }
        {
            int cl = w * 32 + l15;
            float bb0 = b1[ch * 256 + cl];
            float bb1v = b1[ch * 256 + cl + 16];
            #pragma unroll
            for (int r = 0; r < 4; ++r) {
                hb[q4 + r][cl]           = f2bf(gelu_exact(acc1[0][0][r] + bb0));
                hb[q4 + r][cl + 16]      = f2bf(gelu_exact(acc1[0][1][r] + bb1v));
                hb[16 + q4 + r][cl]      = f2bf(gelu_exact(acc1[1][0][r] + bb0));
                hb[16 + q4 + r][cl + 16] = f2bf(gelu_exact(acc1[1][1][r] + bb1v));
            }
        }
        __syncthreads();
        {
            const u16* pw0 = W2B + (size_t)(w * 32 + l15) * FF + ch * 256;
            const u16* pw1 = pw0 + 16 * FF;
            #pragma unroll 4
            for (int k0 = 0; k0 < DM; k0 += 32) {
                s8bf a0 = *(const s8bf*)&hb[l15][k0 + q8];
                s8bf a1 = *(const s8bf*)&hb[16 + l15][k0 + q8];
                s8bf b0 = *(const s8bf*)(pw0 + k0 + q8);
                s8bf b1 = *(const s8bf*)(pw1 + k0 + q8);
                acc2[0][0] = mfma_bf16(a0, b0, acc2[0][0]);
                acc2[1][0] = mfma_bf16(a1, b0, acc2[1][0]);
                acc2[0][1] = mfma_bf16(a0, b1, acc2[0][1]);
                acc2[1][1] = mfma_bf16(a1, b1, acc2[1][1]);
            }
        }
        __syncthreads();
    }

    // ---- LN2 halves: dump -> barrier -> LN2(half) + direct coalesced store -> barrier ----
    auto ln2_half = [&](f4 an0, f4 an1, int hf) {
        {
            int cl = w * 32 + l15;
            #pragma unroll
            for (int r = 0; r < 4; ++r) {
                sb16[q4 + r][cl] = an0[r];
                sb16[q4 + r][cl + 16] = an1[r];
            }
        }
        __syncthreads();
        {
            int r16 = tid >> 5, c8 = (tid & 31) * 8;
            int row = hf * 16 + r16;
            const float* bp = b2 + c8;
            float tv[8];
            float sum = 0.f;
            #pragma unroll
            for (int j = 0; j < 8; j += 4) {
                float4 bv = *(const float4*)(bp + j);
                float t0 = bf2f(xb[row][c8 + j])     + sb16[r16][c8 + j]     + bv.x;
                float t1 = bf2f(xb[row][c8 + j + 1]) + sb16[r16][c8 + j + 1] + bv.y;
                float t2 = bf2f(xb[row][c8 + j + 2]) + sb16[r16][c8 + j + 2] + bv.z;
                float t3 = bf2f(xb[row][c8 + j + 3]) + sb16[r16][c8 + j + 3] + bv.w;
                tv[j] = t0; tv[j+1] = t1; tv[j+2] = t2; tv[j+3] = t3;
                sum += t0 + t1 + t2 + t3;
            }
            sum += __shfl_xor(sum, 1, 32); sum += __shfl_xor(sum, 2, 32);
            sum += __shfl_xor(sum, 4, 32); sum += __shfl_xor(sum, 8, 32);
            sum += __shfl_xor(sum, 16, 32);
            float mu = sum * (1.0f / DM);
            float vs = 0.f;
            #pragma unroll
            for (int j = 0; j < 8; ++j) { float dd = tv[j] - mu; vs += dd * dd; }
            vs += __shfl_xor(vs, 1, 32); vs += __shfl_xor(vs, 2, 32);
            vs += __shfl_xor(vs, 4, 32); vs += __shfl_xor(vs, 8, 32);
            vs += __shfl_xor(vs, 16, 32);
            float rs = rsqrtf(vs * (1.0f / DM) + 1e-5f);
            size_t gr = (size_t)(row >> 1) * N_GENES + (size_t)(n0 + (row & 1));
            float* op = out + gr * DM + c8;
            float4 y0, y1;
            y0.x = (tv[0] - mu) * rs * g2[c8 + 0] + bb2[c8 + 0];
            y0.y = (tv[1] - mu) * rs * g2[c8 + 1] + bb2[c8 + 1];
            y0.z = (tv[2] - mu) * rs * g2[c8 + 2] + bb2[c8 + 2];
            y0.w = (tv[3] - mu) * rs * g2[c8 + 3] + bb2[c8 + 3];
            y1.x = (tv[4] - mu) * rs * g2[c8 + 4] + bb2[c8 + 4];
            y1.y = (tv[5] - mu) * rs * g2[c8 + 5] + bb2[c8 + 5];
            y1.z = (tv[6] - mu) * rs * g2[c8 + 6] + bb2[c8 + 6];
            y1.w = (tv[7] - mu) * rs * g2[c8 + 7] + bb2[c8 + 7];
            *(float4*)(op) = y0;
            *(float4*)(op + 4) = y1;
        }
        __syncthreads();
    };
    ln2_half(acc2[0][0], acc2[0][1], 0);
    ln2_half(acc2[1][0], acc2[1][1], 1);
}

// ================= fallback path (ws too small for weight staging): R3-proven VALU =================
__global__ __launch_bounds__(256) void attn_fb_kernel(
    const float* __restrict__ Hg, const float* __restrict__ kbuf, const float* __restrict__ vbuf,
    const int* __restrict__ assign, const float* __restrict__ Win, const float* __restrict__ bin,
    const float* __restrict__ Wout, const float* __restrict__ bout,
    const float* __restrict__ ln1g, const float* __restrict__ ln1b,
    float* __restrict__ xout, int P) {
    __shared__ float qs[DM];
    __shared__ float hrow[DM];
    __shared__ float sc[NH][PMAX + 1];
    __shared__ float ctxs[DM];
    __shared__ int asg[PMAX];
    __shared__ float red[4];

    int n = blockIdx.x, b = blockIdx.y, tid = threadIdx.x;
    if (tid < P) asg[tid] = assign[tid];
    hrow[tid] = Hg[(size_t)n * DM + tid];
    __syncthreads();
    {
        const float4* wr = (const float4*)(Win + (size_t)tid * DM);
        float acc = bin[tid];
        #pragma unroll 4
        for (int k = 0; k < DM / 4; ++k) {
            float4 w = wr[k];
            acc += w.x * hrow[4*k] + w.y * hrow[4*k+1] + w.z * hrow[4*k+2] + w.w * hrow[4*k+3];
        }
        qs[tid] = acc * 0.17677669529663687f;
        __syncthreads();
    }
    int start = 0, cnt = 0;
    for (int p = 0; p < P; ++p) { int a = asg[p]; start += (a < b); cnt += (a == b); }
    for (int idx = tid; idx < NH * cnt; idx += 256) {
        int h = idx & (NH - 1), pl = idx >> 3;
        const float* krow = kbuf + (size_t)(start + pl) * DM + h * DHEAD;
        const float* qh = qs + h * DHEAD;
        float acc = 0.f;
        #pragma unroll
        for (int e = 0; e < DHEAD; ++e) acc += qh[e] * krow[e];
        sc[h][pl] = acc;
    }
    __syncthreads();
    if (cnt > 0) {
        int h = tid >> 5, ll = tid & 31;
        float m = -INFINITY;
        for (int p = ll; p < cnt; p += 32) m = fmaxf(m, sc[h][p]);
        #pragma unroll
        for (int off = 16; off > 0; off >>= 1) m = fmaxf(m, __shfl_xor(m, off, 32));
        float s = 0.f;
        for (int p = ll; p < cnt; p += 32) { float e = __expf(sc[h][p] - m); sc[h][p] = e; s += e; }
        #pragma unroll
        for (int off = 16; off > 0; off >>= 1) s += __shfl_xor(s, off, 32);
        float inv = 1.0f / s;
        for (int p = ll; p < cnt; p += 32) sc[h][p] *= inv;
    }
    __syncthreads();
    {
        int hh = tid >> 5, e = tid & 31;
        float acc = 0.f;
        for (int p = 0; p < cnt; ++p)
            acc += sc[hh][p] * vbuf[(size_t)(start + p) * DM + hh * DHEAD + e];
        ctxs[tid] = acc;
    }
    __syncthreads();
    float ao = 0.f;
    if (cnt > 0) {
        ao = bout[tid];
        const float4* wr = (const float4*)(Wout + (size_t)tid * DM);
        #pragma unroll 4
        for (int k = 0; k < DM / 4; ++k) {
            float4 w = wr[k];
            ao += w.x * ctxs[4*k] + w.y * ctxs[4*k+1] + w.z * ctxs[4*k+2] + w.w * ctxs[4*k+3];
        }
    }
    float t = hrow[tid] + ao;
    {
        float v = t;
        #pragma unroll
        for (int off = 32; off > 0; off >>= 1) v += __shfl_down(v, off, 64);
        if ((tid & 63) == 0) red[tid >> 6] = v;
        __syncthreads();
        float mu = (red[0] + red[1] + red[2] + red[3]) * (1.0f / DM);
        __syncthreads();
        float dv = t - mu, v2 = dv * dv;
        #pragma unroll
        for (int off = 32; off > 0; off >>= 1) v2 += __shfl_down(v2, off, 64);
        if ((tid & 63) == 0) red[tid >> 6] = v2;
        __syncthreads();
        float var = (red[0] + red[1] + red[2] + red[3]) * (1.0f / DM);
        float xv = dv * rsqrtf(var + 1e-5f) * ln1g[tid] + ln1b[tid];
        xout[((size_t)b * N_GENES + n) * DM + tid] = xv;
    }
}

__global__ __launch_bounds__(256) void ffn_fb_kernel(
    float* __restrict__ xio, const float* __restrict__ W1, const float* __restrict__ b1,
    const float* __restrict__ W2, const float* __restrict__ b2,
    const float* __restrict__ ln2g, const float* __restrict__ ln2b) {
    __shared__ float xs[4][DM];
    __shared__ float hs[4][FF];
    __shared__ float red[4];
    int tid = threadIdx.x;
    size_t row0 = (size_t)blockIdx.x * 4;
    for (int i = tid; i < 4 * DM; i += 256)
        ((float*)xs)[i] = xio[row0 * DM + i];
    __syncthreads();
    for (int oi = 0; oi < FF / 256; ++oi) {
        int o = oi * 256 + tid;
        float bb = b1[o];
        float a0 = bb, a1 = bb, a2 = bb, a3 = bb;
        const float4* wr = (const float4*)(W1 + (size_t)o * DM);
        #pragma unroll 2
        for (int k = 0; k < DM / 4; ++k) {
            float4 w = wr[k];
            a0 += w.x * xs[0][4*k] + w.y * xs[0][4*k+1] + w.z * xs[0][4*k+2] + w.w * xs[0][4*k+3];
            a1 += w.x * xs[1][4*k] + w.y * xs[1][4*k+1] + w.z * xs[1][4*k+2] + w.w * xs[1][4*k+3];
            a2 += w.x * xs[2][4*k] + w.y * xs[2][4*k+1] + w.z * xs[2][4*k+2] + w.w * xs[2][4*k+3];
            a3 += w.x * xs[3][4*k] + w.y * xs[3][4*k+1] + w.z * xs[3][4*k+2] + w.w * xs[3][4*k+3];
        }
        hs[0][o] = gelu_exact(a0); hs[1][o] = gelu_exact(a1);
        hs[2][o] = gelu_exact(a2); hs[3][o] = gelu_exact(a3);
    }
    __syncthreads();
    int d = tid;
    float bb2 = b2[d];
    float c0 = bb2, c1 = bb2, c2 = bb2, c3 = bb2;
    const float4* wr = (const float4*)(W2 + (size_t)d * FF);
    #pragma unroll 2
    for (int k = 0; k < FF / 4; ++k) {
        float4 w = wr[k];
        c0 += w.x * hs[0][4*k] + w.y * hs[0][4*k+1] + w.z * hs[0][4*k+2] + w.w * hs[0][4*k+3];
        c1 += w.x * hs[1][4*k] + w.y * hs[1][4*k+1] + w.z * hs[1][4*k+2] + w.w * hs[1][4*k+3];
        c2 += w.x * hs[2][4*k] + w.y * hs[2][4*k+1] + w.z * hs[2][4*k+2] + w.w * hs[2][4*k+3];
        c3 += w.x * hs[3][4*k] + w.y * hs[3][4*k+1] + w.z * hs[3][4*k+2] + w.w * hs[3][4*k+3];
    }
    float cr[4] = {c0, c1, c2, c3};
    float g = ln2g[d], bln = ln2b[d];
    #pragma unroll
    for (int r = 0; r < 4; ++r) {
        float t = cr[r] + xs[r][d];
        float v = t;
        #pragma unroll
        for (int off = 32; off > 0; off >>= 1) v += __shfl_down(v, off, 64);
        if ((tid & 63) == 0) red[tid >> 6] = v;
        __syncthreads();
        float mu = (red[0] + red[1] + red[2] + red[3]) * (1.0f / DM);
        __syncthreads();
        float dv = t - mu, v2 = dv * dv;
        #pragma unroll
        for (int off = 32; off > 0; off >>= 1) v2 += __shfl_down(v2, off, 64);
        if ((tid & 63) == 0) red[tid >> 6] = v2;
        __syncthreads();
        float var = (red[0] + red[1] + red[2] + red[3]) * (1.0f / DM);
        float y = dv * rsqrtf(var + 1e-5f) * g + bln;
        xio[(row0 + r) * DM + d] = y;
        __syncthreads();
    }
}

extern "C" void kernel_launch(void* const* d_in, const int* in_sizes, int n_in,
                              void* d_out, int out_size, void* d_ws, size_t ws_size,
                              hipStream_t stream) {
    const float* Hg   = (const float*)d_in[0];
    const int* pidx   = (const int*)d_in[1];
    const int* assign = (const int*)d_in[2];
    const float* in_w = (const float*)d_in[4];
    const float* in_b = (const float*)d_in[5];
    const float* out_w= (const float*)d_in[6];
    const float* out_b= (const float*)d_in[7];
    const float* w1   = (const float*)d_in[8];
    const float* b1   = (const float*)d_in[9];
    const float* w2   = (const float*)d_in[10];
    const float* b2   = (const float*)d_in[11];
    const float* g1   = (const float*)d_in[12];
    const float* bb1  = (const float*)d_in[13];
    const float* g2   = (const float*)d_in[14];
    const float* bb2  = (const float*)d_in[15];

    int P = in_sizes[1];
    int B = out_size / (N_GENES * DM);
    size_t nrows = (size_t)B * N_GENES;
    float* out = (float*)d_out;

    size_t woB = (size_t)DM * DM;          // 65536
    size_t w1B = (size_t)FF * DM;          // 262144
    size_t w2B = (size_t)DM * FF;          // 262144
    size_t wbytes = (woB + w1B + w2B) * sizeof(u16);   // 1,179,648
    size_t kvbytes = 2 * (size_t)P * DM * sizeof(float);

    if (ws_size >= wbytes + kvbytes && P <= PMAX && B == 16 && (N_GENES % 2) == 0) {
        // fully fused MFMA path (2 genes x 16 batches per block, 512 threads)
        u16* WoB  = (u16*)d_ws;
        u16* W1Bp = WoB + woB;
        u16* W2Bp = W1Bp + w1B;
        float* kbuf = (float*)(W2Bp + w2B);
        float* vbuf = kbuf + (size_t)P * DM;

        cvt_kernel<<<(int)((woB + 255) / 256), 256, 0, stream>>>(out_w, WoB, (int)woB);
        cvt_kernel<<<(int)((w1B + 255) / 256), 256, 0, stream>>>(w1, W1Bp, (int)w1B);
        cvt_kernel<<<(int)((w2B + 255) / 256), 256, 0, stream>>>(w2, W2Bp, (int)w2B);
        kvproj_kernel<<<P, 256, 0, stream>>>(Hg, pidx, in_w, in_b, kbuf, vbuf);
        fused_all_kernel<<<N_GENES / 2, 512, 0, stream>>>(
            Hg, in_w, in_b, kbuf, vbuf, assign,
            WoB, out_b, W1Bp, b1, W2Bp, b2, g1, bb1, g2, bb2, out, P, B);
    } else {
        // fallback: R3-proven VALU path (kv only in ws)
        float* kbuf = (float*)d_ws;
        float* vbuf = kbuf + (size_t)P * DM;
        kvproj_kernel<<<P, 256, 0, stream>>>(Hg, pidx, in_w, in_b, kbuf, vbuf);
        attn_fb_kernel<<<dim3(N_GENES, B), 256, 0, stream>>>(
            Hg, kbuf, vbuf, assign, in_w, in_b, out_w, out_b, g1, bb1, out, P);
        ffn_fb_kernel<<<(unsigned)(nrows / 4), 256, 0, stream>>>(
            out, w1, b1, w2, b2, g2, bb2);
    }
}

// Round 5
// 492.826 us; speedup vs baseline: 2.2957x; 1.6706x over previous
//
#include <hip/hip_runtime.h>
#include <math.h>

// Problem constants: N=6000, D=256, H=8, DH=32, P=128, B=16. fp32 in/out.
#define N_GENES 6000
#define DM 256
#define NH 8
#define DHEAD 32
#define FF 1024
#define PMAX 128
#define MT 64     // rows per block = 4 genes x 16 batches
#define LDX 264   // u16 inner stride for xb/hb (132 words == 4 mod 32: <=2-way on A-frag reads)

typedef unsigned short u16;
typedef unsigned int u32;
typedef __attribute__((ext_vector_type(8))) short s8bf;  // 8 bf16 in 4 VGPRs
typedef __attribute__((ext_vector_type(4))) float f4;

__device__ __forceinline__ f4 mfma_bf16(s8bf a, s8bf b, f4 c) {
    return __builtin_amdgcn_mfma_f32_16x16x32_bf16(a, b, c, 0, 0, 0);
}

__device__ __forceinline__ float bf2f(u16 u) { return __uint_as_float(((u32)u) << 16); }
__device__ __forceinline__ u16 f2bf(float f) {
    u32 x = __float_as_uint(f);
    return (u16)((x + 0x7fffu + ((x >> 16) & 1u)) >> 16);  // RNE
}
__device__ __forceinline__ float gelu_exact(float x) {
    return 0.5f * x * (1.0f + erff(x * 0.70710678118654752f));
}

// ---- pack W[N][K] fp32 row-major -> bf16 MFMA-fragment order ----
// chunk c: lane = c&63, k0i = (c>>6)%(K/32), nt = c/(64*(K/32))
// dst[c*8+j] = bf16(W[(nt*16+(lane&15))*K + k0i*32 + (lane>>4)*8 + j])
// => in-kernel, lane l's B-frag for (nt,k0i) is 16B at dst + ((nt*KT+k0i)*64+l)*8: 1KB contiguous per wave.
__global__ __launch_bounds__(256) void pack_kernel(const float* __restrict__ src,
                                                   u16* __restrict__ dst, int N, int K) {
    int c = blockIdx.x * 256 + threadIdx.x;
    int KT = K >> 5;
    int total = (N >> 4) * KT * 64;
    if (c >= total) return;
    int lane = c & 63;
    int k0i = (c >> 6) % KT;
    int nt = c / (KT << 6);
    const float* s = src + (size_t)(nt * 16 + (lane & 15)) * K + k0i * 32 + (lane >> 4) * 8;
    u16* d = dst + (size_t)c * 8;
    #pragma unroll
    for (int j = 0; j < 8; ++j) d[j] = f2bf(s[j]);
}

// ---- Wq transpose (fp32): dst[k*256+d] = src[d*256+k]  (coalesced q-proj reads) ----
__global__ __launch_bounds__(256) void transpose_kernel(const float* __restrict__ src,
                                                        float* __restrict__ dst) {
    int i = blockIdx.x * 256 + threadIdx.x;   // i = k*256 + d
    int k = i >> 8, d = i & 255;
    dst[i] = src[(size_t)d * DM + k];
}

// ---------------- k/v projection for the P gathered rows (fp32) ----------------
__global__ __launch_bounds__(256) void kvproj_kernel(
    const float* __restrict__ Hg, const int* __restrict__ pidx,
    const float* __restrict__ Win, const float* __restrict__ bin,
    float* __restrict__ kbuf, float* __restrict__ vbuf) {
    __shared__ float xs[DM];
    int p = blockIdx.x, d = threadIdx.x;
    int row = pidx[p];
    xs[d] = Hg[(size_t)row * DM + d];
    __syncthreads();
    const float4* wk = (const float4*)(Win + (size_t)(DM + d) * DM);
    const float4* wv = (const float4*)(Win + (size_t)(2 * DM + d) * DM);
    float ak = bin[DM + d];
    float av = bin[2 * DM + d];
    #pragma unroll 4
    for (int k = 0; k < DM / 4; ++k) {
        float4 a = wk[k], b = wv[k];
        float x0 = xs[4*k], x1 = xs[4*k+1], x2 = xs[4*k+2], x3 = xs[4*k+3];
        ak += a.x * x0 + a.y * x1 + a.z * x2 + a.w * x3;
        av += b.x * x0 + b.y * x1 + b.z * x2 + b.w * x3;
    }
    kbuf[(size_t)p * DM + d] = ak;
    vbuf[(size_t)p * DM + d] = av;
}

// ==== fully fused, 4 genes x 16 batches per block (64 rows), 512 threads ====
// Packed weights: 1KB contiguous B-frag loads. LDS ~68KB -> 2 blocks/CU; (512,4) -> 128 VGPR budget.
__global__ __launch_bounds__(512, 4) void fused_all_kernel(
    const float* __restrict__ Hg, const float* __restrict__ WqT,
    const float* __restrict__ bin,
    const float* __restrict__ kbuf, const float* __restrict__ vbuf,
    const int* __restrict__ assign,
    const u16* __restrict__ WoP, const float* __restrict__ bout,
    const u16* __restrict__ W1P, const float* __restrict__ b1p,
    const u16* __restrict__ W2P, const float* __restrict__ b2p,
    const float* __restrict__ g1, const float* __restrict__ bb1,
    const float* __restrict__ g2, const float* __restrict__ bb2,
    float* __restrict__ out, int P, int B) {

    __shared__ __align__(16) u16 xb[MT][LDX];             // 33,792 B: ctx(bf16) then x(bf16)
    __shared__ __align__(16) char reg2_raw[32 * 264 * 4]; // 33,792 B time-shared
    __shared__ int asg[PMAX];
    __shared__ int startb[16];
    __shared__ int cntb[16];
    __shared__ float hasb[16];

    float* reg2f = (float*)reg2_raw;
    // early phases (all fit in 8448 floats):
    float (*sc)[132] = (float(*)[132])reg2f;     // [32][132] = 4224 floats
    float* qs   = reg2f + 4224;                  // [32][34]  = 1088
    float* hrow = reg2f + 5312;                  // [4][256]  = 1024
    float* ps   = reg2f + 6336;                  // [4][2][256] = 2048 -> 8384 total
    // later phases (alias whole region):
    float (*sb32)[264] = (float(*)[264])reg2_raw;  // [32][264] f32 GEMM dump (half rows)
    u16  (*hb)[LDX]    = (u16 (*)[LDX])reg2_raw;   // [64][264] bf16 hidden chunk

    const f4 fzero = {0.f, 0.f, 0.f, 0.f};
    int tid = threadIdx.x;
    int w = tid >> 6, l = tid & 63;
    int l15 = l & 15, q8 = (l >> 4) * 8, q4 = (l >> 4) * 4;
    int n0 = blockIdx.x * 4;   // 4 genes per block
    // row r in [0,64): gene gi = r&3, batch b = r>>2

    // ---- P0: stage assignment + 4 gene rows ----
    if (tid < P) asg[tid] = assign[tid];
    for (int i = tid; i < 4 * DM; i += 512)
        hrow[i] = Hg[(size_t)n0 * DM + i];
    __syncthreads();
    if (tid < 16) {
        int s = 0, c = 0;
        for (int p = 0; p < P; ++p) { int a = asg[p]; s += (a < tid); c += (a == tid); }
        startb[tid] = s; cntb[tid] = c; hasb[tid] = c ? 1.f : 0.f;
    }

    // ---- P1: qproj split-k, coalesced WqT reads. thread (d=tid&255, kh=tid>>8). ----
    {
        int d = tid & 255, kh = tid >> 8;
        const float* wt = WqT + (size_t)(kh * 128) * DM + d;
        float a0 = 0.f, a1 = 0.f, a2 = 0.f, a3 = 0.f;
        const float* h0 = hrow + kh * 128;
        #pragma unroll 8
        for (int k = 0; k < 128; ++k) {
            float wv = wt[(size_t)k * DM];
            a0 += wv * h0[k];
            a1 += wv * h0[256 + k];
            a2 += wv * h0[512 + k];
            a3 += wv * h0[768 + k];
        }
        ps[0 * 512 + kh * 256 + d] = a0;
        ps[1 * 512 + kh * 256 + d] = a1;
        ps[2 * 512 + kh * 256 + d] = a2;
        ps[3 * 512 + kh * 256 + d] = a3;
    }
    __syncthreads();
    for (int i = tid; i < 1024; i += 512) {
        int g = i >> 8, d = i & 255;
        float q = (ps[g * 512 + d] + ps[g * 512 + 256 + d] + bin[d]) * 0.17677669529663687f;
        qs[(g * 8 + (d >> 5)) * 34 + (d & 31)] = q;
    }
    __syncthreads();

    // ---- P2a: all scores once. gh = idx&31 (g=gh>>3,h=gh&7), p = idx>>5. ----
    for (int idx = tid; idx < 32 * P; idx += 512) {
        int gh = idx & 31, p = idx >> 5;
        const float* qp = qs + gh * 34;
        const float4* kr = (const float4*)(kbuf + (size_t)p * DM + (gh & 7) * DHEAD);
        float dsum = 0.f;
        #pragma unroll
        for (int e = 0; e < 8; ++e) {
            float4 kv = kr[e];
            dsum += qp[4*e] * kv.x + qp[4*e+1] * kv.y + qp[4*e+2] * kv.z + qp[4*e+3] * kv.w;
        }
        sc[gh][p] = dsum;
    }
    __syncthreads();

    // ---- P2b: softmax + ctx; 512 tasks = 512 threads: (r = tid>>3, h = tid&7). ----
    {
        int r = tid >> 3, h = tid & 7;
        int gi = r & 3, bb = r >> 2;
        int s = startb[bb], c = cntb[bb];
        float4 cx[8];
        #pragma unroll
        for (int e = 0; e < 8; ++e) cx[e] = make_float4(0.f, 0.f, 0.f, 0.f);
        if (c > 0) {
            const float* scp = sc[gi * 8 + h];
            float m = -INFINITY;
            for (int i = 0; i < c; ++i) m = fmaxf(m, scp[s + i]);
            float sum = 0.f;
            const float* vb0 = vbuf + h * DHEAD;
            for (int i = 0; i < c; ++i) {
                float wgt = __expf(scp[s + i] - m);
                sum += wgt;
                const float4* vr = (const float4*)(vb0 + (size_t)(s + i) * DM);
                #pragma unroll
                for (int e = 0; e < 8; ++e) {
                    float4 vvv = vr[e];
                    cx[e].x += wgt * vvv.x; cx[e].y += wgt * vvv.y;
                    cx[e].z += wgt * vvv.z; cx[e].w += wgt * vvv.w;
                }
            }
            float inv = 1.0f / sum;
            #pragma unroll
            for (int e = 0; e < 8; ++e) {
                cx[e].x *= inv; cx[e].y *= inv; cx[e].z *= inv; cx[e].w *= inv;
            }
        }
        u16* xrow = &xb[r][h * DHEAD];
        #pragma unroll
        for (int e = 0; e < 8; ++e) {
            *(u32*)(xrow + 4 * e)     = (u32)f2bf(cx[e].x) | ((u32)f2bf(cx[e].y) << 16);
            *(u32*)(xrow + 4 * e + 2) = (u32)f2bf(cx[e].z) | ((u32)f2bf(cx[e].w) << 16);
        }
    }
    __syncthreads();

    // ---- P3: GEMM0: ctx @ Wout^T; wave w -> col tiles nt {2w, 2w+1}, all 4 row tiles ----
    f4 acc[4][2] = {fzero, fzero, fzero, fzero, fzero, fzero, fzero, fzero};
    {
        const u16* pb0 = WoP + (size_t)w * 8192 + (size_t)l * 8;   // nt0=2w, KT=8
        #pragma unroll 4
        for (int k0i = 0; k0i < 8; ++k0i) {
            int k0 = k0i * 32;
            s8bf a0 = *(const s8bf*)&xb[l15][k0 + q8];
            s8bf a1 = *(const s8bf*)&xb[16 + l15][k0 + q8];
            s8bf a2 = *(const s8bf*)&xb[32 + l15][k0 + q8];
            s8bf a3 = *(const s8bf*)&xb[48 + l15][k0 + q8];
            s8bf b0 = *(const s8bf*)(pb0 + k0i * 512);
            s8bf b1 = *(const s8bf*)(pb0 + 4096 + k0i * 512);
            acc[0][0] = mfma_bf16(a0, b0, acc[0][0]);
            acc[1][0] = mfma_bf16(a1, b0, acc[1][0]);
            acc[2][0] = mfma_bf16(a2, b0, acc[2][0]);
            acc[3][0] = mfma_bf16(a3, b0, acc[3][0]);
            acc[0][1] = mfma_bf16(a0, b1, acc[0][1]);
            acc[1][1] = mfma_bf16(a1, b1, acc[1][1]);
            acc[2][1] = mfma_bf16(a2, b1, acc[2][1]);
            acc[3][1] = mfma_bf16(a3, b1, acc[3][1]);
        }
    }

    // ---- LN1 in two 32-row halves: dump -> barrier -> LN1 -> barrier ----
    auto ln1_pass = [&](int hf, f4 aA0, f4 aA1, f4 aB0, f4 aB1) {
        int cl = w * 32 + l15;
        #pragma unroll
        for (int r = 0; r < 4; ++r) {
            sb32[q4 + r][cl]           = aA0[r];
            sb32[q4 + r][cl + 16]      = aA1[r];
            sb32[16 + q4 + r][cl]      = aB0[r];
            sb32[16 + q4 + r][cl + 16] = aB1[r];
        }
        __syncthreads();
        int r32 = tid >> 4, c4 = (tid & 15) * 4;
        int row = hf * 32 + r32;
        int gi = row & 3, bb = row >> 2;
        float has = hasb[bb];
        const float* hp = Hg + (size_t)(n0 + gi) * DM;
        float tv[16];
        float sum = 0.f;
        #pragma unroll
        for (int jg = 0; jg < 4; ++jg) {
            int c = c4 + jg * 64;
            float4 hv = *(const float4*)(hp + c);
            float4 bv = *(const float4*)(bout + c);
            float t0 = hv.x + has * (sb32[r32][c]     + bv.x);
            float t1 = hv.y + has * (sb32[r32][c + 1] + bv.y);
            float t2 = hv.z + has * (sb32[r32][c + 2] + bv.z);
            float t3 = hv.w + has * (sb32[r32][c + 3] + bv.w);
            tv[jg*4] = t0; tv[jg*4+1] = t1; tv[jg*4+2] = t2; tv[jg*4+3] = t3;
            sum += t0 + t1 + t2 + t3;
        }
        sum += __shfl_xor(sum, 1, 16); sum += __shfl_xor(sum, 2, 16);
        sum += __shfl_xor(sum, 4, 16); sum += __shfl_xor(sum, 8, 16);
        float mu = sum * (1.0f / DM);
        float vs = 0.f;
        #pragma unroll
        for (int j = 0; j < 16; ++j) { float dd = tv[j] - mu; vs += dd * dd; }
        vs += __shfl_xor(vs, 1, 16); vs += __shfl_xor(vs, 2, 16);
        vs += __shfl_xor(vs, 4, 16); vs += __shfl_xor(vs, 8, 16);
        float rs = rsqrtf(vs * (1.0f / DM) + 1e-5f);
        #pragma unroll
        for (int jg = 0; jg < 4; ++jg) {
            int c = c4 + jg * 64;
            float x0 = (tv[jg*4]     - mu) * rs * g1[c]     + bb1[c];
            float x1 = (tv[jg*4 + 1] - mu) * rs * g1[c + 1] + bb1[c + 1];
            float x2 = (tv[jg*4 + 2] - mu) * rs * g1[c + 2] + bb1[c + 2];
            float x3 = (tv[jg*4 + 3] - mu) * rs * g1[c + 3] + bb1[c + 3];
            *(u32*)&xb[row][c]     = (u32)f2bf(x0) | ((u32)f2bf(x1) << 16);
            *(u32*)&xb[row][c + 2] = (u32)f2bf(x2) | ((u32)f2bf(x3) << 16);
        }
        __syncthreads();
    };
    ln1_pass(0, acc[0][0], acc[0][1], acc[1][0], acc[1][1]);
    ln1_pass(1, acc[2][0], acc[2][1], acc[3][0], acc[3][1]);

    // ---- P4: FFN: 4 chunks of 256 hidden cols; GEMM1 -> hb -> GEMM2 accumulate ----
    f4 acc2[4][2] = {fzero, fzero, fzero, fzero, fzero, fzero, fzero, fzero};
    for (int ch = 0; ch < 4; ++ch) {
        f4 acc1[4][2] = {fzero, fzero, fzero, fzero, fzero, fzero, fzero, fzero};
        {
            const u16* pb0 = W1P + (size_t)(ch * 16 + 2 * w) * 4096 + (size_t)l * 8;  // KT=8
            #pragma unroll 4
            for (int k0i = 0; k0i < 8; ++k0i) {
                int k0 = k0i * 32;
                s8bf a0 = *(const s8bf*)&xb[l15][k0 + q8];
                s8bf a1 = *(const s8bf*)&xb[16 + l15][k0 + q8];
                s8bf a2 = *(const s8bf*)&xb[32 + l15][k0 + q8];
                s8bf a3 = *(const s8bf*)&xb[48 + l15][k0 + q8];
                s8bf b0 = *(const s8bf*)(pb0 + k0i * 512);
                s8bf b1 = *(const s8bf*)(pb0 + 4096 + k0i * 512);
                acc1[0][0] = mfma_bf16(a0, b0, acc1[0][0]);
                acc1[1][0] = mfma_bf16(a1, b0, acc1[1][0]);
                acc1[2][0] = mfma_bf16(a2, b0, acc1[2][0]);
                acc1[3][0] = mfma_bf16(a3, b0, acc1[3][0]);
                acc1[0][1] = mfma_bf16(a0, b1, acc1[0][1]);
                acc1[1][1] = mfma_bf16(a1, b1, acc1[1][1]);
                acc1[2][1] = mfma_bf16(a2, b1, acc1[2][1]);
                acc1[3][1] = mfma_bf16(a3, b1, acc1[3][1]);
            }
        }
        {
            int cl = w * 32 + l15;
            float bbA = b1p[ch * 256 + cl];
            float bbB = b1p[ch * 256 + cl + 16];
            #pragma unroll
            for (int mt = 0; mt < 4; ++mt)
                #pragma unroll
                for (int r = 0; r < 4; ++r) {
                    hb[mt * 16 + q4 + r][cl]      = f2bf(gelu_exact(acc1[mt][0][r] + bbA));
                    hb[mt * 16 + q4 + r][cl + 16] = f2bf(gelu_exact(acc1[mt][1][r] + bbB));
                }
        }
        __syncthreads();
        {
            const u16* pb0 = W2P + (size_t)(2 * w) * 16384 + (size_t)(ch * 8) * 512 + (size_t)l * 8;  // KT=32
            #pragma unroll 4
            for (int k0i = 0; k0i < 8; ++k0i) {
                int k0 = k0i * 32;
                s8bf a0 = *(const s8bf*)&hb[l15][k0 + q8];
                s8bf a1 = *(const s8bf*)&hb[16 + l15][k0 + q8];
                s8bf a2 = *(const s8bf*)&hb[32 + l15][k0 + q8];
                s8bf a3 = *(const s8bf*)&hb[48 + l15][k0 + q8];
                s8bf b0 = *(const s8bf*)(pb0 + k0i * 512);
                s8bf b1 = *(const s8bf*)(pb0 + 16384 + k0i * 512);
                acc2[0][0] = mfma_bf16(a0, b0, acc2[0][0]);
                acc2[1][0] = mfma_bf16(a1, b0, acc2[1][0]);
                acc2[2][0] = mfma_bf16(a2, b0, acc2[2][0]);
                acc2[3][0] = mfma_bf16(a3, b0, acc2[3][0]);
                acc2[0][1] = mfma_bf16(a0, b1, acc2[0][1]);
                acc2[1][1] = mfma_bf16(a1, b1, acc2[1][1]);
                acc2[2][1] = mfma_bf16(a2, b1, acc2[2][1]);
                acc2[3][1] = mfma_bf16(a3, b1, acc2[3][1]);
            }
        }
        __syncthreads();
    }

    // ---- LN2 in two 32-row halves: dump -> barrier -> LN2 + direct store -> barrier ----
    auto ln2_pass = [&](int hf, f4 aA0, f4 aA1, f4 aB0, f4 aB1) {
        int cl = w * 32 + l15;
        #pragma unroll
        for (int r = 0; r < 4; ++r) {
            sb32[q4 + r][cl]           = aA0[r];
            sb32[q4 + r][cl + 16]      = aA1[r];
            sb32[16 + q4 + r][cl]      = aB0[r];
            sb32[16 + q4 + r][cl + 16] = aB1[r];
        }
        __syncthreads();
        int r32 = tid >> 4, c4 = (tid & 15) * 4;
        int row = hf * 32 + r32;
        int gi = row & 3, bb = row >> 2;
        float tv[16];
        float sum = 0.f;
        #pragma unroll
        for (int jg = 0; jg < 4; ++jg) {
            int c = c4 + jg * 64;
            float4 bv = *(const float4*)(b2p + c);
            float t0 = bf2f(xb[row][c])     + sb32[r32][c]     + bv.x;
            float t1 = bf2f(xb[row][c + 1]) + sb32[r32][c + 1] + bv.y;
            float t2 = bf2f(xb[row][c + 2]) + sb32[r32][c + 2] + bv.z;
            float t3 = bf2f(xb[row][c + 3]) + sb32[r32][c + 3] + bv.w;
            tv[jg*4] = t0; tv[jg*4+1] = t1; tv[jg*4+2] = t2; tv[jg*4+3] = t3;
            sum += t0 + t1 + t2 + t3;
        }
        sum += __shfl_xor(sum, 1, 16); sum += __shfl_xor(sum, 2, 16);
        sum += __shfl_xor(sum, 4, 16); sum += __shfl_xor(sum, 8, 16);
        float mu = sum * (1.0f / DM);
        float vs = 0.f;
        #pragma unroll
        for (int j = 0; j < 16; ++j) { float dd = tv[j] - mu; vs += dd * dd; }
        vs += __shfl_xor(vs, 1, 16); vs += __shfl_xor(vs, 2, 16);
        vs += __shfl_xor(vs, 4, 16); vs += __shfl_xor(vs, 8, 16);
        float rs = rsqrtf(vs * (1.0f / DM) + 1e-5f);
        size_t gr = (size_t)bb * N_GENES + (size_t)(n0 + gi);
        float* op = out + gr * DM;
        #pragma unroll
        for (int jg = 0; jg < 4; ++jg) {
            int c = c4 + jg * 64;
            float4 y;
            y.x = (tv[jg*4]     - mu) * rs * g2[c]     + bb2[c];
            y.y = (tv[jg*4 + 1] - mu) * rs * g2[c + 1] + bb2[c + 1];
            y.z = (tv[jg*4 + 2] - mu) * rs * g2[c + 2] + bb2[c + 2];
            y.w = (tv[jg*4 + 3] - mu) * rs * g2[c + 3] + bb2[c + 3];
            *(float4*)(op + c) = y;
        }
        __syncthreads();
    };
    ln2_pass(0, acc2[0][0], acc2[0][1], acc2[1][0], acc2[1][1]);
    ln2_pass(1, acc2[2][0], acc2[2][1], acc2[3][0], acc2[3][1]);
}

// ================= fallback path (ws too small): R3-proven VALU =================
__global__ __launch_bounds__(256) void attn_fb_kernel(
    const float* __restrict__ Hg, const float* __restrict__ kbuf, const float* __restrict__ vbuf,
    const int* __restrict__ assign, const float* __restrict__ Win, const float* __restrict__ bin,
    const float* __restrict__ Wout, const float* __restrict__ bout,
    const float* __restrict__ ln1g, const float* __restrict__ ln1b,
    float* __restrict__ xout, int P) {
    __shared__ float qs[DM];
    __shared__ float hrow[DM];
    __shared__ float sc[NH][PMAX + 1];
    __shared__ float ctxs[DM];
    __shared__ int asg[PMAX];
    __shared__ float red[4];

    int n = blockIdx.x, b = blockIdx.y, tid = threadIdx.x;
    if (tid < P) asg[tid] = assign[tid];
    hrow[tid] = Hg[(size_t)n * DM + tid];
    __syncthreads();
    {
        const float4* wr = (const float4*)(Win + (size_t)tid * DM);
        float acc = bin[tid];
        #pragma unroll 4
        for (int k = 0; k < DM / 4; ++k) {
            float4 w = wr[k];
            acc += w.x * hrow[4*k] + w.y * hrow[4*k+1] + w.z * hrow[4*k+2] + w.w * hrow[4*k+3];
        }
        qs[tid] = acc * 0.17677669529663687f;
        __syncthreads();
    }
    int start = 0, cnt = 0;
    for (int p = 0; p < P; ++p) { int a = asg[p]; start += (a < b); cnt += (a == b); }
    for (int idx = tid; idx < NH * cnt; idx += 256) {
        int h = idx & (NH - 1), pl = idx >> 3;
        const float* krow = kbuf + (size_t)(start + pl) * DM + h * DHEAD;
        const float* qh = qs + h * DHEAD;
        float acc = 0.f;
        #pragma unroll
        for (int e = 0; e < DHEAD; ++e) acc += qh[e] * krow[e];
        sc[h][pl] = acc;
    }
    __syncthreads();
    if (cnt > 0) {
        int h = tid >> 5, ll = tid & 31;
        float m = -INFINITY;
        for (int p = ll; p < cnt; p += 32) m = fmaxf(m, sc[h][p]);
        #pragma unroll
        for (int off = 16; off > 0; off >>= 1) m = fmaxf(m, __shfl_xor(m, off, 32));
        float s = 0.f;
        for (int p = ll; p < cnt; p += 32) { float e = __expf(sc[h][p] - m); sc[h][p] = e; s += e; }
        #pragma unroll
        for (int off = 16; off > 0; off >>= 1) s += __shfl_xor(s, off, 32);
        float inv = 1.0f / s;
        for (int p = ll; p < cnt; p += 32) sc[h][p] *= inv;
    }
    __syncthreads();
    {
        int hh = tid >> 5, e = tid & 31;
        float acc = 0.f;
        for (int p = 0; p < cnt; ++p)
            acc += sc[hh][p] * vbuf[(size_t)(start + p) * DM + hh * DHEAD + e];
        ctxs[tid] = acc;
    }
    __syncthreads();
    float ao = 0.f;
    if (cnt > 0) {
        ao = bout[tid];
        const float4* wr = (const float4*)(Wout + (size_t)tid * DM);
        #pragma unroll 4
        for (int k = 0; k < DM / 4; ++k) {
            float4 w = wr[k];
            ao += w.x * ctxs[4*k] + w.y * ctxs[4*k+1] + w.z * ctxs[4*k+2] + w.w * ctxs[4*k+3];
        }
    }
    float t = hrow[tid] + ao;
    {
        float v = t;
        #pragma unroll
        for (int off = 32; off > 0; off >>= 1) v += __shfl_down(v, off, 64);
        if ((tid & 63) == 0) red[tid >> 6] = v;
        __syncthreads();
        float mu = (red[0] + red[1] + red[2] + red[3]) * (1.0f / DM);
        __syncthreads();
        float dv = t - mu, v2 = dv * dv;
        #pragma unroll
        for (int off = 32; off > 0; off >>= 1) v2 += __shfl_down(v2, off, 64);
        if ((tid & 63) == 0) red[tid >> 6] = v2;
        __syncthreads();
        float var = (red[0] + red[1] + red[2] + red[3]) * (1.0f / DM);
        float xv = dv * rsqrtf(var + 1e-5f) * ln1g[tid] + ln1b[tid];
        xout[((size_t)b * N_GENES + n) * DM + tid] = xv;
    }
}

__global__ __launch_bounds__(256) void ffn_fb_kernel(
    float* __restrict__ xio, const float* __restrict__ W1, const float* __restrict__ b1,
    const float* __restrict__ W2, const float* __restrict__ b2,
    const float* __restrict__ ln2g, const float* __restrict__ ln2b) {
    __shared__ float xs[4][DM];
    __shared__ float hs[4][FF];
    __shared__ float red[4];
    int tid = threadIdx.x;
    size_t row0 = (size_t)blockIdx.x * 4;
    for (int i = tid; i < 4 * DM; i += 256)
        ((float*)xs)[i] = xio[row0 * DM + i];
    __syncthreads();
    for (int oi = 0; oi < FF / 256; ++oi) {
        int o = oi * 256 + tid;
        float bb = b1[o];
        float a0 = bb, a1 = bb, a2 = bb, a3 = bb;
        const float4* wr = (const float4*)(W1 + (size_t)o * DM);
        #pragma unroll 2
        for (int k = 0; k < DM / 4; ++k) {
            float4 w = wr[k];
            a0 += w.x * xs[0][4*k] + w.y * xs[0][4*k+1] + w.z * xs[0][4*k+2] + w.w * xs[0][4*k+3];
            a1 += w.x * xs[1][4*k] + w.y * xs[1][4*k+1] + w.z * xs[1][4*k+2] + w.w * xs[1][4*k+3];
            a2 += w.x * xs[2][4*k] + w.y * xs[2][4*k+1] + w.z * xs[2][4*k+2] + w.w * xs[2][4*k+3];
            a3 += w.x * xs[3][4*k] + w.y * xs[3][4*k+1] + w.z * xs[3][4*k+2] + w.w * xs[3][4*k+3];
        }
        hs[0][o] = gelu_exact(a0); hs[1][o] = gelu_exact(a1);
        hs[2][o] = gelu_exact(a2); hs[3][o] = gelu_exact(a3);
    }
    __syncthreads();
    int d = tid;
    float bb2 = b2[d];
    float c0 = bb2, c1 = bb2, c2 = bb2, c3 = bb2;
    const float4* wr = (const float4*)(W2 + (size_t)d * FF);
    #pragma unroll 2
    for (int k = 0; k < FF / 4; ++k) {
        float4 w = wr[k];
        c0 += w.x * hs[0][4*k] + w.y * hs[0][4*k+1] + w.z * hs[0][4*k+2] + w.w * hs[0][4*k+3];
        c1 += w.x * hs[1][4*k] + w.y * hs[1][4*k+1] + w.z * hs[1][4*k+2] + w.w * hs[1][4*k+3];
        c2 += w.x * hs[2][4*k] + w.y * hs[2][4*k+1] + w.z * hs[2][4*k+2] + w.w * hs[2][4*k+3];
        c3 += w.x * hs[3][4*k] + w.y * hs[3][4*k+1] + w.z * hs[3][4*k+2] + w.w * hs[3][4*k+3];
    }
    float cr[4] = {c0, c1, c2, c3};
    float g = ln2g[d], bln = ln2b[d];
    #pragma unroll
    for (int r = 0; r < 4; ++r) {
        float t = cr[r] + xs[r][d];
        float v = t;
        #pragma unroll
        for (int off = 32; off > 0; off >>= 1) v += __shfl_down(v, off, 64);
        if ((tid & 63) == 0) red[tid >> 6] = v;
        __syncthreads();
        float mu = (red[0] + red[1] + red[2] + red[3]) * (1.0f / DM);
        __syncthreads();
        float dv = t - mu, v2 = dv * dv;
        #pragma unroll
        for (int off = 32; off > 0; off >>= 1) v2 += __shfl_down(v2, off, 64);
        if ((tid & 63) == 0) red[tid >> 6] = v2;
        __syncthreads();
        float var = (red[0] + red[1] + red[2] + red[3]) * (1.0f / DM);
        float y = dv * rsqrtf(var + 1e-5f) * g + bln;
        xio[(row0 + r) * DM + d] = y;
        __syncthreads();
    }
}

extern "C" void kernel_launch(void* const* d_in, const int* in_sizes, int n_in,
                              void* d_out, int out_size, void* d_ws, size_t ws_size,
                              hipStream_t stream) {
    const float* Hg   = (const float*)d_in[0];
    const int* pidx   = (const int*)d_in[1];
    const int* assign = (const int*)d_in[2];
    const float* in_w = (const float*)d_in[4];
    const float* in_b = (const float*)d_in[5];
    const float* out_w= (const float*)d_in[6];
    const float* out_b= (const float*)d_in[7];
    const float* w1   = (const float*)d_in[8];
    const float* b1   = (const float*)d_in[9];
    const float* w2   = (const float*)d_in[10];
    const float* b2   = (const float*)d_in[11];
    const float* g1   = (const float*)d_in[12];
    const float* bb1  = (const float*)d_in[13];
    const float* g2   = (const float*)d_in[14];
    const float* bb2  = (const float*)d_in[15];

    int P = in_sizes[1];
    int B = out_size / (N_GENES * DM);
    size_t nrows = (size_t)B * N_GENES;
    float* out = (float*)d_out;

    size_t woB = (size_t)DM * DM;          // 65536
    size_t w1B = (size_t)FF * DM;          // 262144
    size_t w2B = (size_t)DM * FF;          // 262144
    size_t wqTf = (size_t)DM * DM;         // 65536 fp32
    size_t wbytes = (woB + w1B + w2B) * sizeof(u16) + wqTf * sizeof(float);  // 1,441,792
    size_t kvbytes = 2 * (size_t)P * DM * sizeof(float);

    if (ws_size >= wbytes + kvbytes && P <= PMAX && B == 16 && (N_GENES % 4) == 0) {
        // fused MFMA path (4 genes x 16 batches per block, 512 threads, packed weights)
        u16* WoP  = (u16*)d_ws;
        u16* W1P  = WoP + woB;
        u16* W2P  = W1P + w1B;
        float* WqT = (float*)(W2P + w2B);
        float* kbuf = WqT + wqTf;
        float* vbuf = kbuf + (size_t)P * DM;

        pack_kernel<<<32, 256, 0, stream>>>(out_w, WoP, DM, DM);
        pack_kernel<<<128, 256, 0, stream>>>(w1, W1P, FF, DM);
        pack_kernel<<<128, 256, 0, stream>>>(w2, W2P, DM, FF);
        transpose_kernel<<<256, 256, 0, stream>>>(in_w, WqT);
        kvproj_kernel<<<P, 256, 0, stream>>>(Hg, pidx, in_w, in_b, kbuf, vbuf);
        fused_all_kernel<<<N_GENES / 4, 512, 0, stream>>>(
            Hg, WqT, in_b, kbuf, vbuf, assign,
            WoP, out_b, W1P, b1, W2P, b2, g1, bb1, g2, bb2, out, P, B);
    } else {
        // fallback: R3-proven VALU path (kv only in ws)
        float* kbuf = (float*)d_ws;
        float* vbuf = kbuf + (size_t)P * DM;
        kvproj_kernel<<<P, 256, 0, stream>>>(Hg, pidx, in_w, in_b, kbuf, vbuf);
        attn_fb_kernel<<<dim3(N_GENES, B), 256, 0, stream>>>(
            Hg, kbuf, vbuf, assign, in_w, in_b, out_w, out_b, g1, bb1, out, P);
        ffn_fb_kernel<<<(unsigned)(nrows / 4), 256, 0, stream>>>(
            out, w1, b1, w2, b2, g2, bb2);
    }
}

// Round 6
// 484.330 us; speedup vs baseline: 2.3359x; 1.0175x over previous
//
#include <hip/hip_runtime.h>
#include <math.h>

// Problem constants: N=6000, D=256, H=8, DH=32, P=128, B=16. fp32 in/out.
#define N_GENES 6000
#define DM 256
#define NH 8
#define DHEAD 32
#define FF 1024
#define PMAX 128
#define MT 64     // rows per block = 4 genes x 16 batches
#define LDX 264   // u16 inner stride for xb/hb (132 words == 4 mod 32: <=2-way on A-frag reads)
#define LDF 260   // f32 inner stride for sb32 (4*260 == 16 mod 32: 2-way (free) on epilogue dumps)

typedef unsigned short u16;
typedef unsigned int u32;
typedef __attribute__((ext_vector_type(8))) short s8bf;  // 8 bf16 in 4 VGPRs
typedef __attribute__((ext_vector_type(4))) float f4;

__device__ __forceinline__ f4 mfma_bf16(s8bf a, s8bf b, f4 c) {
    return __builtin_amdgcn_mfma_f32_16x16x32_bf16(a, b, c, 0, 0, 0);
}

__device__ __forceinline__ float bf2f(u16 u) { return __uint_as_float(((u32)u) << 16); }
__device__ __forceinline__ u16 f2bf(float f) {
    u32 x = __float_as_uint(f);
    return (u16)((x + 0x7fffu + ((x >> 16) & 1u)) >> 16);  // RNE
}
__device__ __forceinline__ float gelu_exact(float x) {
    return 0.5f * x * (1.0f + erff(x * 0.70710678118654752f));
}
// fast erf (Abramowitz-Stegun 7.1.26, |err| <= 1.5e-7): invisible under bf16 quantization of hb
__device__ __forceinline__ float gelu_fast(float x) {
    float z = fabsf(x) * 0.70710678118654752f;
    float t = 1.0f / (1.0f + 0.3275911f * z);
    float poly = t * (0.254829592f + t * (-0.284496736f + t * (1.421413741f +
                 t * (-1.453152027f + t * 1.061405429f))));
    float erf_abs = 1.0f - poly * __expf(-z * z);
    float erfv = copysignf(erf_abs, x);
    return 0.5f * x * (1.0f + erfv);
}

// ==== single prologue kernel: pack Wo/W1/W2 + tiled Wq transpose + kvproj ====
// blocks [0,32): pack Wo; [32,160): pack W1; [160,288): pack W2; [288,352): WqT; [352,352+P): kvproj
// pack: chunk c -> lane=c&63, k0i=(c>>6)%KT, nt=c/(64*KT);
//   dst[c*8+j] = bf16(src[(nt*16+(lane&15))*K + k0i*32 + (lane>>4)*8 + j])
//   => lane l's B-frag for (nt,k0i) is 16B at dst+((nt*KT+k0i)*64+l)*8 : 1KB contiguous per wave.
__global__ __launch_bounds__(256) void prep_kernel(
    const float* __restrict__ Hg, const int* __restrict__ pidx,
    const float* __restrict__ in_w, const float* __restrict__ in_b,
    const float* __restrict__ out_w, const float* __restrict__ w1,
    const float* __restrict__ w2,
    u16* __restrict__ WoP, u16* __restrict__ W1P, u16* __restrict__ W2P,
    float* __restrict__ WqT, float* __restrict__ kbuf, float* __restrict__ vbuf,
    int P) {
    __shared__ float ts[32][33];   // transpose tile
    __shared__ float xs[DM];       // kvproj row
    int blk = blockIdx.x, tid = threadIdx.x;
    if (blk < 288) {
        const float* src; u16* dst; int K; int c;
        if (blk < 32)       { src = out_w; dst = WoP; K = DM; c = blk * 256 + tid; }
        else if (blk < 160) { src = w1;    dst = W1P; K = DM; c = (blk - 32) * 256 + tid; }
        else                { src = w2;    dst = W2P; K = FF; c = (blk - 160) * 256 + tid; }
        int KT = K >> 5;
        int lane = c & 63;
        int k0i = (c >> 6) % KT;
        int nt = c / (KT << 6);
        const float* s = src + (size_t)(nt * 16 + (lane & 15)) * K + k0i * 32 + (lane >> 4) * 8;
        u16* d = dst + (size_t)c * 8;
        #pragma unroll
        for (int j = 0; j < 8; ++j) d[j] = f2bf(s[j]);
    } else if (blk < 352) {
        // WqT[k*256+d] = Wq[d*256+k] via 32x32 LDS tile
        int tile = blk - 288;
        int tr = tile >> 3, tc = tile & 7;
        int lane = tid & 31, rowg = tid >> 5;
        #pragma unroll
        for (int i = 0; i < 4; ++i) {
            int r = rowg * 4 + i;
            ts[r][lane] = in_w[(size_t)(tr * 32 + r) * DM + tc * 32 + lane];
        }
        __syncthreads();
        #pragma unroll
        for (int i = 0; i < 4; ++i) {
            int a = rowg * 4 + i;
            WqT[(size_t)(tc * 32 + a) * DM + tr * 32 + lane] = ts[lane][a];
        }
    } else {
        int p = blk - 352;
        if (p >= P) return;
        int d = tid;
        int row = pidx[p];
        xs[d] = Hg[(size_t)row * DM + d];
        __syncthreads();
        const float4* wk = (const float4*)(in_w + (size_t)(DM + d) * DM);
        const float4* wv = (const float4*)(in_w + (size_t)(2 * DM + d) * DM);
        float ak = in_b[DM + d];
        float av = in_b[2 * DM + d];
        #pragma unroll 4
        for (int k = 0; k < DM / 4; ++k) {
            float4 a = wk[k], b = wv[k];
            float x0 = xs[4*k], x1 = xs[4*k+1], x2 = xs[4*k+2], x3 = xs[4*k+3];
            ak += a.x * x0 + a.y * x1 + a.z * x2 + a.w * x3;
            av += b.x * x0 + b.y * x1 + b.z * x2 + b.w * x3;
        }
        kbuf[(size_t)p * DM + d] = ak;
        vbuf[(size_t)p * DM + d] = av;
    }
}

// ---------------- standalone kvproj (fallback path only) ----------------
__global__ __launch_bounds__(256) void kvproj_kernel(
    const float* __restrict__ Hg, const int* __restrict__ pidx,
    const float* __restrict__ Win, const float* __restrict__ bin,
    float* __restrict__ kbuf, float* __restrict__ vbuf) {
    __shared__ float xs[DM];
    int p = blockIdx.x, d = threadIdx.x;
    int row = pidx[p];
    xs[d] = Hg[(size_t)row * DM + d];
    __syncthreads();
    const float4* wk = (const float4*)(Win + (size_t)(DM + d) * DM);
    const float4* wv = (const float4*)(Win + (size_t)(2 * DM + d) * DM);
    float ak = bin[DM + d];
    float av = bin[2 * DM + d];
    #pragma unroll 4
    for (int k = 0; k < DM / 4; ++k) {
        float4 a = wk[k], b = wv[k];
        float x0 = xs[4*k], x1 = xs[4*k+1], x2 = xs[4*k+2], x3 = xs[4*k+3];
        ak += a.x * x0 + a.y * x1 + a.z * x2 + a.w * x3;
        av += b.x * x0 + b.y * x1 + b.z * x2 + b.w * x3;
    }
    kbuf[(size_t)p * DM + d] = ak;
    vbuf[(size_t)p * DM + d] = av;
}

// ==== fully fused, 4 genes x 16 batches per block (64 rows), 512 threads ====
__global__ __launch_bounds__(512, 4) void fused_all_kernel(
    const float* __restrict__ Hg, const float* __restrict__ WqT,
    const float* __restrict__ bin,
    const float* __restrict__ kbuf, const float* __restrict__ vbuf,
    const int* __restrict__ assign,
    const u16* __restrict__ WoP, const float* __restrict__ bout,
    const u16* __restrict__ W1P, const float* __restrict__ b1p,
    const u16* __restrict__ W2P, const float* __restrict__ b2p,
    const float* __restrict__ g1, const float* __restrict__ bb1,
    const float* __restrict__ g2, const float* __restrict__ bb2,
    float* __restrict__ out, int P, int B) {

    __shared__ __align__(16) u16 xb[MT][LDX];             // 33,792 B: ctx(bf16) then x(bf16)
    __shared__ __align__(16) char reg2_raw[MT * LDX * 2]; // 33,792 B time-shared
    __shared__ int asg[PMAX];
    __shared__ int startb[16];
    __shared__ int cntb[16];
    __shared__ float hasb[16];

    float* reg2f = (float*)reg2_raw;
    // early phases (8384 floats <= 8448):
    float (*sc)[132] = (float(*)[132])reg2f;     // [32][132]
    float* qs   = reg2f + 4224;                  // [32][34]
    float* hrow = reg2f + 5312;                  // [4][256]
    float* ps   = reg2f + 6336;                  // [4][2][256]
    // later phases (alias whole region):
    float (*sb32)[LDF] = (float(*)[LDF])reg2_raw;  // [32][260] f32 GEMM dump
    u16  (*hb)[LDX]    = (u16 (*)[LDX])reg2_raw;   // [64][264] bf16 hidden chunk

    const f4 fzero = {0.f, 0.f, 0.f, 0.f};
    int tid = threadIdx.x;
    int w = tid >> 6, l = tid & 63;
    int l15 = l & 15, q8 = (l >> 4) * 8, q4 = (l >> 4) * 4;
    int n0 = blockIdx.x * 4;   // 4 genes per block
    // row r in [0,64): gene gi = r&3, batch b = r>>2

    // ---- P0: stage assignment + 4 gene rows ----
    if (tid < P) asg[tid] = assign[tid];
    for (int i = tid; i < 4 * DM; i += 512)
        hrow[i] = Hg[(size_t)n0 * DM + i];
    __syncthreads();
    if (tid < 16) {
        int s = 0, c = 0;
        for (int p = 0; p < P; ++p) { int a = asg[p]; s += (a < tid); c += (a == tid); }
        startb[tid] = s; cntb[tid] = c; hasb[tid] = c ? 1.f : 0.f;
    }

    // ---- P1: qproj split-k, coalesced WqT reads. thread (d=tid&255, kh=tid>>8). ----
    {
        int d = tid & 255, kh = tid >> 8;
        const float* wt = WqT + (size_t)(kh * 128) * DM + d;
        float a0 = 0.f, a1 = 0.f, a2 = 0.f, a3 = 0.f;
        const float* h0 = hrow + kh * 128;
        #pragma unroll 8
        for (int k = 0; k < 128; ++k) {
            float wv = wt[(size_t)k * DM];
            a0 += wv * h0[k];
            a1 += wv * h0[256 + k];
            a2 += wv * h0[512 + k];
            a3 += wv * h0[768 + k];
        }
        ps[0 * 512 + kh * 256 + d] = a0;
        ps[1 * 512 + kh * 256 + d] = a1;
        ps[2 * 512 + kh * 256 + d] = a2;
        ps[3 * 512 + kh * 256 + d] = a3;
    }
    __syncthreads();
    for (int i = tid; i < 1024; i += 512) {
        int g = i >> 8, d = i & 255;
        float q = (ps[g * 512 + d] + ps[g * 512 + 256 + d] + bin[d]) * 0.17677669529663687f;
        qs[(g * 8 + (d >> 5)) * 34 + (d & 31)] = q;
    }
    __syncthreads();

    // ---- P2a: all scores once. gh = idx&31 (g=gh>>3,h=gh&7), p = idx>>5. ----
    for (int idx = tid; idx < 32 * P; idx += 512) {
        int gh = idx & 31, p = idx >> 5;
        const float* qp = qs + gh * 34;
        const float4* kr = (const float4*)(kbuf + (size_t)p * DM + (gh & 7) * DHEAD);
        float dsum = 0.f;
        #pragma unroll
        for (int e = 0; e < 8; ++e) {
            float4 kv = kr[e];
            dsum += qp[4*e] * kv.x + qp[4*e+1] * kv.y + qp[4*e+2] * kv.z + qp[4*e+3] * kv.w;
        }
        sc[gh][p] = dsum;
    }
    __syncthreads();

    // ---- P2b: softmax + ctx; 512 tasks: (r = tid>>3, h = tid&7). ----
    {
        int r = tid >> 3, h = tid & 7;
        int gi = r & 3, bb = r >> 2;
        int s = startb[bb], c = cntb[bb];
        float4 cx[8];
        #pragma unroll
        for (int e = 0; e < 8; ++e) cx[e] = make_float4(0.f, 0.f, 0.f, 0.f);
        if (c > 0) {
            const float* scp = sc[gi * 8 + h];
            float m = -INFINITY;
            for (int i = 0; i < c; ++i) m = fmaxf(m, scp[s + i]);
            float sum = 0.f;
            const float* vb0 = vbuf + h * DHEAD;
            for (int i = 0; i < c; ++i) {
                float wgt = __expf(scp[s + i] - m);
                sum += wgt;
                const float4* vr = (const float4*)(vb0 + (size_t)(s + i) * DM);
                #pragma unroll
                for (int e = 0; e < 8; ++e) {
                    float4 vvv = vr[e];
                    cx[e].x += wgt * vvv.x; cx[e].y += wgt * vvv.y;
                    cx[e].z += wgt * vvv.z; cx[e].w += wgt * vvv.w;
                }
            }
            float inv = 1.0f / sum;
            #pragma unroll
            for (int e = 0; e < 8; ++e) {
                cx[e].x *= inv; cx[e].y *= inv; cx[e].z *= inv; cx[e].w *= inv;
            }
        }
        u16* xrow = &xb[r][h * DHEAD];
        #pragma unroll
        for (int e = 0; e < 8; ++e) {
            *(u32*)(xrow + 4 * e)     = (u32)f2bf(cx[e].x) | ((u32)f2bf(cx[e].y) << 16);
            *(u32*)(xrow + 4 * e + 2) = (u32)f2bf(cx[e].z) | ((u32)f2bf(cx[e].w) << 16);
        }
    }
    __syncthreads();

    // ---- P3: GEMM0 (ctx @ Wout^T), 2-stage prefetch of A- and B-frags ----
    f4 acc[4][2] = {fzero, fzero, fzero, fzero, fzero, fzero, fzero, fzero};
    {
        const u16* pb = WoP + (size_t)w * 8192 + (size_t)l * 8;   // nt {2w,2w+1}, KT=8
        s8bf b0 = *(const s8bf*)(pb);
        s8bf b1 = *(const s8bf*)(pb + 4096);
        s8bf a0 = *(const s8bf*)&xb[l15][q8];
        s8bf a1 = *(const s8bf*)&xb[16 + l15][q8];
        s8bf a2 = *(const s8bf*)&xb[32 + l15][q8];
        s8bf a3 = *(const s8bf*)&xb[48 + l15][q8];
        #pragma unroll
        for (int k0i = 0; k0i < 8; ++k0i) {
            s8bf nb0, nb1, na0, na1, na2, na3;
            if (k0i < 7) {
                nb0 = *(const s8bf*)(pb + (k0i + 1) * 512);
                nb1 = *(const s8bf*)(pb + 4096 + (k0i + 1) * 512);
                int k0 = (k0i + 1) * 32 + q8;
                na0 = *(const s8bf*)&xb[l15][k0];
                na1 = *(const s8bf*)&xb[16 + l15][k0];
                na2 = *(const s8bf*)&xb[32 + l15][k0];
                na3 = *(const s8bf*)&xb[48 + l15][k0];
            }
            acc[0][0] = mfma_bf16(a0, b0, acc[0][0]);
            acc[1][0] = mfma_bf16(a1, b0, acc[1][0]);
            acc[2][0] = mfma_bf16(a2, b0, acc[2][0]);
            acc[3][0] = mfma_bf16(a3, b0, acc[3][0]);
            acc[0][1] = mfma_bf16(a0, b1, acc[0][1]);
            acc[1][1] = mfma_bf16(a1, b1, acc[1][1]);
            acc[2][1] = mfma_bf16(a2, b1, acc[2][1]);
            acc[3][1] = mfma_bf16(a3, b1, acc[3][1]);
            if (k0i < 7) { b0 = nb0; b1 = nb1; a0 = na0; a1 = na1; a2 = na2; a3 = na3; }
        }
    }

    // ---- LN1 in two 32-row halves: dump -> barrier -> LN1 -> barrier ----
    auto ln1_pass = [&](int hf, f4 aA0, f4 aA1, f4 aB0, f4 aB1) {
        int cl = w * 32 + l15;
        #pragma unroll
        for (int r = 0; r < 4; ++r) {
            sb32[q4 + r][cl]           = aA0[r];
            sb32[q4 + r][cl + 16]      = aA1[r];
            sb32[16 + q4 + r][cl]      = aB0[r];
            sb32[16 + q4 + r][cl + 16] = aB1[r];
        }
        __syncthreads();
        int r32 = tid >> 4, c4 = (tid & 15) * 4;
        int row = hf * 32 + r32;
        int gi = row & 3, bb = row >> 2;
        float has = hasb[bb];
        const float* hp = Hg + (size_t)(n0 + gi) * DM;
        float tv[16];
        float sum = 0.f;
        #pragma unroll
        for (int jg = 0; jg < 4; ++jg) {
            int c = c4 + jg * 64;
            float4 hv = *(const float4*)(hp + c);
            float4 bv = *(const float4*)(bout + c);
            float t0 = hv.x + has * (sb32[r32][c]     + bv.x);
            float t1 = hv.y + has * (sb32[r32][c + 1] + bv.y);
            float t2 = hv.z + has * (sb32[r32][c + 2] + bv.z);
            float t3 = hv.w + has * (sb32[r32][c + 3] + bv.w);
            tv[jg*4] = t0; tv[jg*4+1] = t1; tv[jg*4+2] = t2; tv[jg*4+3] = t3;
            sum += t0 + t1 + t2 + t3;
        }
        sum += __shfl_xor(sum, 1, 16); sum += __shfl_xor(sum, 2, 16);
        sum += __shfl_xor(sum, 4, 16); sum += __shfl_xor(sum, 8, 16);
        float mu = sum * (1.0f / DM);
        float vs = 0.f;
        #pragma unroll
        for (int j = 0; j < 16; ++j) { float dd = tv[j] - mu; vs += dd * dd; }
        vs += __shfl_xor(vs, 1, 16); vs += __shfl_xor(vs, 2, 16);
        vs += __shfl_xor(vs, 4, 16); vs += __shfl_xor(vs, 8, 16);
        float rs = rsqrtf(vs * (1.0f / DM) + 1e-5f);
        #pragma unroll
        for (int jg = 0; jg < 4; ++jg) {
            int c = c4 + jg * 64;
            float x0 = (tv[jg*4]     - mu) * rs * g1[c]     + bb1[c];
            float x1 = (tv[jg*4 + 1] - mu) * rs * g1[c + 1] + bb1[c + 1];
            float x2 = (tv[jg*4 + 2] - mu) * rs * g1[c + 2] + bb1[c + 2];
            float x3 = (tv[jg*4 + 3] - mu) * rs * g1[c + 3] + bb1[c + 3];
            *(u32*)&xb[row][c]     = (u32)f2bf(x0) | ((u32)f2bf(x1) << 16);
            *(u32*)&xb[row][c + 2] = (u32)f2bf(x2) | ((u32)f2bf(x3) << 16);
        }
        __syncthreads();
    };
    ln1_pass(0, acc[0][0], acc[0][1], acc[1][0], acc[1][1]);
    ln1_pass(1, acc[2][0], acc[2][1], acc[3][0], acc[3][1]);

    // ---- P4: FFN: 4 chunks of 256 hidden cols; GEMM1 -> hb -> GEMM2 accumulate ----
    f4 acc2[4][2] = {fzero, fzero, fzero, fzero, fzero, fzero, fzero, fzero};
    for (int ch = 0; ch < 4; ++ch) {
        f4 acc1[4][2] = {fzero, fzero, fzero, fzero, fzero, fzero, fzero, fzero};
        {
            const u16* pb = W1P + (size_t)(ch * 16 + 2 * w) * 4096 + (size_t)l * 8;  // KT=8
            s8bf b0 = *(const s8bf*)(pb);
            s8bf b1 = *(const s8bf*)(pb + 4096);
            #pragma unroll
            for (int k0i = 0; k0i < 8; ++k0i) {
                s8bf nb0, nb1;
                if (k0i < 7) {
                    nb0 = *(const s8bf*)(pb + (k0i + 1) * 512);
                    nb1 = *(const s8bf*)(pb + 4096 + (k0i + 1) * 512);
                }
                int k0 = k0i * 32 + q8;
                s8bf a0 = *(const s8bf*)&xb[l15][k0];
                s8bf a1 = *(const s8bf*)&xb[16 + l15][k0];
                s8bf a2 = *(const s8bf*)&xb[32 + l15][k0];
                s8bf a3 = *(const s8bf*)&xb[48 + l15][k0];
                acc1[0][0] = mfma_bf16(a0, b0, acc1[0][0]);
                acc1[1][0] = mfma_bf16(a1, b0, acc1[1][0]);
                acc1[2][0] = mfma_bf16(a2, b0, acc1[2][0]);
                acc1[3][0] = mfma_bf16(a3, b0, acc1[3][0]);
                acc1[0][1] = mfma_bf16(a0, b1, acc1[0][1]);
                acc1[1][1] = mfma_bf16(a1, b1, acc1[1][1]);
                acc1[2][1] = mfma_bf16(a2, b1, acc1[2][1]);
                acc1[3][1] = mfma_bf16(a3, b1, acc1[3][1]);
                if (k0i < 7) { b0 = nb0; b1 = nb1; }
            }
        }
        {
            int cl = w * 32 + l15;
            float bbA = b1p[ch * 256 + cl];
            float bbB = b1p[ch * 256 + cl + 16];
            #pragma unroll
            for (int mt = 0; mt < 4; ++mt)
                #pragma unroll
                for (int r = 0; r < 4; ++r) {
                    hb[mt * 16 + q4 + r][cl]      = f2bf(gelu_fast(acc1[mt][0][r] + bbA));
                    hb[mt * 16 + q4 + r][cl + 16] = f2bf(gelu_fast(acc1[mt][1][r] + bbB));
                }
        }
        __syncthreads();
        {
            const u16* pb = W2P + (size_t)(2 * w) * 16384 + (size_t)(ch * 8) * 512 + (size_t)l * 8;  // KT=32
            s8bf b0 = *(const s8bf*)(pb);
            s8bf b1 = *(const s8bf*)(pb + 16384);
            #pragma unroll
            for (int k0i = 0; k0i < 8; ++k0i) {
                s8bf nb0, nb1;
                if (k0i < 7) {
                    nb0 = *(const s8bf*)(pb + (k0i + 1) * 512);
                    nb1 = *(const s8bf*)(pb + 16384 + (k0i + 1) * 512);
                }
                int k0 = k0i * 32 + q8;
                s8bf a0 = *(const s8bf*)&hb[l15][k0];
                s8bf a1 = *(const s8bf*)&hb[16 + l15][k0];
                s8bf a2 = *(const s8bf*)&hb[32 + l15][k0];
                s8bf a3 = *(const s8bf*)&hb[48 + l15][k0];
                acc2[0][0] = mfma_bf16(a0, b0, acc2[0][0]);
                acc2[1][0] = mfma_bf16(a1, b0, acc2[1][0]);
                acc2[2][0] = mfma_bf16(a2, b0, acc2[2][0]);
                acc2[3][0] = mfma_bf16(a3, b0, acc2[3][0]);
                acc2[0][1] = mfma_bf16(a0, b1, acc2[0][1]);
                acc2[1][1] = mfma_bf16(a1, b1, acc2[1][1]);
                acc2[2][1] = mfma_bf16(a2, b1, acc2[2][1]);
                acc2[3][1] = mfma_bf16(a3, b1, acc2[3][1]);
                if (k0i < 7) { b0 = nb0; b1 = nb1; }
            }
        }
        __syncthreads();
    }

    // ---- LN2 in two 32-row halves: dump -> barrier -> LN2 + direct store -> barrier ----
    auto ln2_pass = [&](int hf, f4 aA0, f4 aA1, f4 aB0, f4 aB1) {
        int cl = w * 32 + l15;
        #pragma unroll
        for (int r = 0; r < 4; ++r) {
            sb32[q4 + r][cl]           = aA0[r];
            sb32[q4 + r][cl + 16]      = aA1[r];
            sb32[16 + q4 + r][cl]      = aB0[r];
            sb32[16 + q4 + r][cl + 16] = aB1[r];
        }
        __syncthreads();
        int r32 = tid >> 4, c4 = (tid & 15) * 4;
        int row = hf * 32 + r32;
        int gi = row & 3, bb = row >> 2;
        float tv[16];
        float sum = 0.f;
        #pragma unroll
        for (int jg = 0; jg < 4; ++jg) {
            int c = c4 + jg * 64;
            float4 bv = *(const float4*)(b2p + c);
            float t0 = bf2f(xb[row][c])     + sb32[r32][c]     + bv.x;
            float t1 = bf2f(xb[row][c + 1]) + sb32[r32][c + 1] + bv.y;
            float t2 = bf2f(xb[row][c + 2]) + sb32[r32][c + 2] + bv.z;
            float t3 = bf2f(xb[row][c + 3]) + sb32[r32][c + 3] + bv.w;
            tv[jg*4] = t0; tv[jg*4+1] = t1; tv[jg*4+2] = t2; tv[jg*4+3] = t3;
            sum += t0 + t1 + t2 + t3;
        }
        sum += __shfl_xor(sum, 1, 16); sum += __shfl_xor(sum, 2, 16);
        sum += __shfl_xor(sum, 4, 16); sum += __shfl_xor(sum, 8, 16);
        float mu = sum * (1.0f / DM);
        float vs = 0.f;
        #pragma unroll
        for (int j = 0; j < 16; ++j) { float dd = tv[j] - mu; vs += dd * dd; }
        vs += __shfl_xor(vs, 1, 16); vs += __shfl_xor(vs, 2, 16);
        vs += __shfl_xor(vs, 4, 16); vs += __shfl_xor(vs, 8, 16);
        float rs = rsqrtf(vs * (1.0f / DM) + 1e-5f);
        size_t gr = (size_t)bb * N_GENES + (size_t)(n0 + gi);
        float* op = out + gr * DM;
        #pragma unroll
        for (int jg = 0; jg < 4; ++jg) {
            int c = c4 + jg * 64;
            float4 y;
            y.x = (tv[jg*4]     - mu) * rs * g2[c]     + bb2[c];
            y.y = (tv[jg*4 + 1] - mu) * rs * g2[c + 1] + bb2[c + 1];
            y.z = (tv[jg*4 + 2] - mu) * rs * g2[c + 2] + bb2[c + 2];
            y.w = (tv[jg*4 + 3] - mu) * rs * g2[c + 3] + bb2[c + 3];
            *(float4*)(op + c) = y;
        }
        __syncthreads();
    };
    ln2_pass(0, acc2[0][0], acc2[0][1], acc2[1][0], acc2[1][1]);
    ln2_pass(1, acc2[2][0], acc2[2][1], acc2[3][0], acc2[3][1]);
}

// ================= fallback path (ws too small): R3-proven VALU =================
__global__ __launch_bounds__(256) void attn_fb_kernel(
    const float* __restrict__ Hg, const float* __restrict__ kbuf, const float* __restrict__ vbuf,
    const int* __restrict__ assign, const float* __restrict__ Win, const float* __restrict__ bin,
    const float* __restrict__ Wout, const float* __restrict__ bout,
    const float* __restrict__ ln1g, const float* __restrict__ ln1b,
    float* __restrict__ xout, int P) {
    __shared__ float qs[DM];
    __shared__ float hrow[DM];
    __shared__ float sc[NH][PMAX + 1];
    __shared__ float ctxs[DM];
    __shared__ int asg[PMAX];
    __shared__ float red[4];

    int n = blockIdx.x, b = blockIdx.y, tid = threadIdx.x;
    if (tid < P) asg[tid] = assign[tid];
    hrow[tid] = Hg[(size_t)n * DM + tid];
    __syncthreads();
    {
        const float4* wr = (const float4*)(Win + (size_t)tid * DM);
        float acc = bin[tid];
        #pragma unroll 4
        for (int k = 0; k < DM / 4; ++k) {
            float4 w = wr[k];
            acc += w.x * hrow[4*k] + w.y * hrow[4*k+1] + w.z * hrow[4*k+2] + w.w * hrow[4*k+3];
        }
        qs[tid] = acc * 0.17677669529663687f;
        __syncthreads();
    }
    int start = 0, cnt = 0;
    for (int p = 0; p < P; ++p) { int a = asg[p]; start += (a < b); cnt += (a == b); }
    for (int idx = tid; idx < NH * cnt; idx += 256) {
        int h = idx & (NH - 1), pl = idx >> 3;
        const float* krow = kbuf + (size_t)(start + pl) * DM + h * DHEAD;
        const float* qh = qs + h * DHEAD;
        float acc = 0.f;
        #pragma unroll
        for (int e = 0; e < DHEAD; ++e) acc += qh[e] * krow[e];
        sc[h][pl] = acc;
    }
    __syncthreads();
    if (cnt > 0) {
        int h = tid >> 5, ll = tid & 31;
        float m = -INFINITY;
        for (int p = ll; p < cnt; p += 32) m = fmaxf(m, sc[h][p]);
        #pragma unroll
        for (int off = 16; off > 0; off >>= 1) m = fmaxf(m, __shfl_xor(m, off, 32));
        float s = 0.f;
        for (int p = ll; p < cnt; p += 32) { float e = __expf(sc[h][p] - m); sc[h][p] = e; s += e; }
        #pragma unroll
        for (int off = 16; off > 0; off >>= 1) s += __shfl_xor(s, off, 32);
        float inv = 1.0f / s;
        for (int p = ll; p < cnt; p += 32) sc[h][p] *= inv;
    }
    __syncthreads();
    {
        int hh = tid >> 5, e = tid & 31;
        float acc = 0.f;
        for (int p = 0; p < cnt; ++p)
            acc += sc[hh][p] * vbuf[(size_t)(start + p) * DM + hh * DHEAD + e];
        ctxs[tid] = acc;
    }
    __syncthreads();
    float ao = 0.f;
    if (cnt > 0) {
        ao = bout[tid];
        const float4* wr = (const float4*)(Wout + (size_t)tid * DM);
        #pragma unroll 4
        for (int k = 0; k < DM / 4; ++k) {
            float4 w = wr[k];
            ao += w.x * ctxs[4*k] + w.y * ctxs[4*k+1] + w.z * ctxs[4*k+2] + w.w * ctxs[4*k+3];
        }
    }
    float t = hrow[tid] + ao;
    {
        float v = t;
        #pragma unroll
        for (int off = 32; off > 0; off >>= 1) v += __shfl_down(v, off, 64);
        if ((tid & 63) == 0) red[tid >> 6] = v;
        __syncthreads();
        float mu = (red[0] + red[1] + red[2] + red[3]) * (1.0f / DM);
        __syncthreads();
        float dv = t - mu, v2 = dv * dv;
        #pragma unroll
        for (int off = 32; off > 0; off >>= 1) v2 += __shfl_down(v2, off, 64);
        if ((tid & 63) == 0) red[tid >> 6] = v2;
        __syncthreads();
        float var = (red[0] + red[1] + red[2] + red[3]) * (1.0f / DM);
        float xv = dv * rsqrtf(var + 1e-5f) * ln1g[tid] + ln1b[tid];
        xout[((size_t)b * N_GENES + n) * DM + tid] = xv;
    }
}

__global__ __launch_bounds__(256) void ffn_fb_kernel(
    float* __restrict__ xio, const float* __restrict__ W1, const float* __restrict__ b1,
    const float* __restrict__ W2, const float* __restrict__ b2,
    const float* __restrict__ ln2g, const float* __restrict__ ln2b) {
    __shared__ float xs[4][DM];
    __shared__ float hs[4][FF];
    __shared__ float red[4];
    int tid = threadIdx.x;
    size_t row0 = (size_t)blockIdx.x * 4;
    for (int i = tid; i < 4 * DM; i += 256)
        ((float*)xs)[i] = xio[row0 * DM + i];
    __syncthreads();
    for (int oi = 0; oi < FF / 256; ++oi) {
        int o = oi * 256 + tid;
        float bb = b1[o];
        float a0 = bb, a1 = bb, a2 = bb, a3 = bb;
        const float4* wr = (const float4*)(W1 + (size_t)o * DM);
        #pragma unroll 2
        for (int k = 0; k < DM / 4; ++k) {
            float4 w = wr[k];
            a0 += w.x * xs[0][4*k] + w.y * xs[0][4*k+1] + w.z * xs[0][4*k+2] + w.w * xs[0][4*k+3];
            a1 += w.x * xs[1][4*k] + w.y * xs[1][4*k+1] + w.z * xs[1][4*k+2] + w.w * xs[1][4*k+3];
            a2 += w.x * xs[2][4*k] + w.y * xs[2][4*k+1] + w.z * xs[2][4*k+2] + w.w * xs[2][4*k+3];
            a3 += w.x * xs[3][4*k] + w.y * xs[3][4*k+1] + w.z * xs[3][4*k+2] + w.w * xs[3][4*k+3];
        }
        hs[0][o] = gelu_exact(a0); hs[1][o] = gelu_exact(a1);
        hs[2][o] = gelu_exact(a2); hs[3][o] = gelu_exact(a3);
    }
    __syncthreads();
    int d = tid;
    float bb2 = b2[d];
    float c0 = bb2, c1 = bb2, c2 = bb2, c3 = bb2;
    const float4* wr = (const float4*)(W2 + (size_t)d * FF);
    #pragma unroll 2
    for (int k = 0; k < FF / 4; ++k) {
        float4 w = wr[k];
        c0 += w.x * hs[0][4*k] + w.y * hs[0][4*k+1] + w.z * hs[0][4*k+2] + w.w * hs[0][4*k+3];
        c1 += w.x * hs[1][4*k] + w.y * hs[1][4*k+1] + w.z * hs[1][4*k+2] + w.w * hs[1][4*k+3];
        c2 += w.x * hs[2][4*k] + w.y * hs[2][4*k+1] + w.z * hs[2][4*k+2] + w.w * hs[2][4*k+3];
        c3 += w.x * hs[3][4*k] + w.y * hs[3][4*k+1] + w.z * hs[3][4*k+2] + w.w * hs[3][4*k+3];
    }
    float cr[4] = {c0, c1, c2, c3};
    float g = ln2g[d], bln = ln2b[d];
    #pragma unroll
    for (int r = 0; r < 4; ++r) {
        float t = cr[r] + xs[r][d];
        float v = t;
        #pragma unroll
        for (int off = 32; off > 0; off >>= 1) v += __shfl_down(v, off, 64);
        if ((tid & 63) == 0) red[tid >> 6] = v;
        __syncthreads();
        float mu = (red[0] + red[1] + red[2] + red[3]) * (1.0f / DM);
        __syncthreads();
        float dv = t - mu, v2 = dv * dv;
        #pragma unroll
        for (int off = 32; off > 0; off >>= 1) v2 += __shfl_down(v2, off, 64);
        if ((tid & 63) == 0) red[tid >> 6] = v2;
        __syncthreads();
        float var = (red[0] + red[1] + red[2] + red[3]) * (1.0f / DM);
        float y = dv * rsqrtf(var + 1e-5f) * g + bln;
        xio[(row0 + r) * DM + d] = y;
        __syncthreads();
    }
}

extern "C" void kernel_launch(void* const* d_in, const int* in_sizes, int n_in,
                              void* d_out, int out_size, void* d_ws, size_t ws_size,
                              hipStream_t stream) {
    const float* Hg   = (const float*)d_in[0];
    const int* pidx   = (const int*)d_in[1];
    const int* assign = (const int*)d_in[2];
    const float* in_w = (const float*)d_in[4];
    const float* in_b = (const float*)d_in[5];
    const float* out_w= (const float*)d_in[6];
    const float* out_b= (const float*)d_in[7];
    const float* w1   = (const float*)d_in[8];
    const float* b1   = (const float*)d_in[9];
    const float* w2   = (const float*)d_in[10];
    const float* b2   = (const float*)d_in[11];
    const float* g1   = (const float*)d_in[12];
    const float* bb1  = (const float*)d_in[13];
    const float* g2   = (const float*)d_in[14];
    const float* bb2  = (const float*)d_in[15];

    int P = in_sizes[1];
    int B = out_size / (N_GENES * DM);
    size_t nrows = (size_t)B * N_GENES;
    float* out = (float*)d_out;

    size_t woB = (size_t)DM * DM;          // 65536
    size_t w1B = (size_t)FF * DM;          // 262144
    size_t w2B = (size_t)DM * FF;          // 262144
    size_t wqTf = (size_t)DM * DM;         // 65536 fp32
    size_t wbytes = (woB + w1B + w2B) * sizeof(u16) + wqTf * sizeof(float);  // 1,441,792
    size_t kvbytes = 2 * (size_t)P * DM * sizeof(float);

    if (ws_size >= wbytes + kvbytes && P <= PMAX && B == 16 && (N_GENES % 4) == 0) {
        // fused MFMA path (4 genes x 16 batches per block, 512 threads, packed weights)
        u16* WoP  = (u16*)d_ws;
        u16* W1P  = WoP + woB;
        u16* W2P  = W1P + w1B;
        float* WqT = (float*)(W2P + w2B);
        float* kbuf = WqT + wqTf;
        float* vbuf = kbuf + (size_t)P * DM;

        prep_kernel<<<352 + P, 256, 0, stream>>>(
            Hg, pidx, in_w, in_b, out_w, w1, w2,
            WoP, W1P, W2P, WqT, kbuf, vbuf, P);
        fused_all_kernel<<<N_GENES / 4, 512, 0, stream>>>(
            Hg, WqT, in_b, kbuf, vbuf, assign,
            WoP, out_b, W1P, b1, W2P, b2, g1, bb1, g2, bb2, out, P, B);
    } else {
        // fallback: R3-proven VALU path (kv only in ws)
        float* kbuf = (float*)d_ws;
        float* vbuf = kbuf + (size_t)P * DM;
        kvproj_kernel<<<P, 256, 0, stream>>>(Hg, pidx, in_w, in_b, kbuf, vbuf);
        attn_fb_kernel<<<dim3(N_GENES, B), 256, 0, stream>>>(
            Hg, kbuf, vbuf, assign, in_w, in_b, out_w, out_b, g1, bb1, out, P);
        ffn_fb_kernel<<<(unsigned)(nrows / 4), 256, 0, stream>>>(
            out, w1, b1, w2, b2, g2, bb2);
    }
}